// Round 2
// baseline (587.994 us; speedup 1.0000x reference)
//
#include <hip/hip_runtime.h>

// ---------------------------------------------------------------------------
// LlamaAttention_Tender: hidden(2048x4096) -> QKV proj -> RoPE -> int8 qdq(K,V)
// -> GQA causal attention (32 q-heads, 8 kv-heads, D=128) -> out proj.
// R4: GEMMs rewritten to the 256x256 8-phase template (T3+T4+T5+T2):
//     BK=64, 512 thr (8 waves, 2Mx4N, per-wave 128x64 interleaved across
//     halves), 1 half-tile (16KB) staged per phase via global_load_lds,
//     counted vmcnt(4) once per K-tile (never 0 in loop), raw s_barrier
//     (no drain), setprio(1) on MFMA clusters, both-sides XOR swizzle.
//     Stage/death schedule: phase q0 stages T+1 Ah1, q1: T+1 Bh1,
//     q2: T+2 Ah0, q3: T+2 Bh0; fence vmcnt(4) at group end (0 in tail).
// ---------------------------------------------------------------------------

#define S_LEN 2048
#define HID 4096
#define NH 32
#define NKV 8
#define HD 128
#define QKV_N 6144   // 4096 q + 1024 k + 1024 v

typedef __bf16 bf16x8 __attribute__((ext_vector_type(8)));
typedef float f32x4 __attribute__((ext_vector_type(4)));

__device__ __forceinline__ unsigned short f2b(float f) {
  unsigned int u = __float_as_uint(f);
  u += 0x7fffu + ((u >> 16) & 1u);   // round-to-nearest-even
  return (unsigned short)(u >> 16);
}
__device__ __forceinline__ float b2f(unsigned short h) {
  return __uint_as_float(((unsigned int)h) << 16);
}
// async global->LDS, 16B per lane. LDS dst must be wave-uniform (lane*16 implicit).
__device__ __forceinline__ void gl_lds16(const void* g, void* l) {
  __builtin_amdgcn_global_load_lds(
      (__attribute__((address_space(1))) void*)g,
      (__attribute__((address_space(3))) void*)l, 16, 0, 0);
}
// LDS bank-spread swizzle: permutes 16B chunks within a 128B row; involution.
__device__ __forceinline__ int swz(int row) {
  return ((row & 7) << 4) ^ (((row >> 3) & 1) << 5);
}
// barrier without the __syncthreads vmcnt(0) drain; asm fences stop IR motion
__device__ __forceinline__ void barrier_np() {
  asm volatile("" ::: "memory");
  __builtin_amdgcn_s_barrier();
  asm volatile("" ::: "memory");
}

// ---------------------------------------------------------------- cast fp32->bf16
__global__ __launch_bounds__(256) void cast_kernel(const float* __restrict__ src,
                                                   unsigned short* __restrict__ dst,
                                                   int n4) {
  int i = blockIdx.x * 256 + threadIdx.x;
  if (i >= n4) return;
  float4 v = ((const float4*)src)[i];
  ushort4 o;
  o.x = f2b(v.x); o.y = f2b(v.y); o.z = f2b(v.z); o.w = f2b(v.w);
  ((ushort4*)dst)[i] = o;
}

// --------------------------------------------- B^T GEMM, 256x256 8-phase template
// C[M,N] = A[M,K]*B[N,K]^T. 512 thr = 8 waves (2Mx4N), per-wave out 128x64
// (rows: mh*128 + wave_m*64 + mi*16, cols: nh*128 + wave_n*32 + ni*16).
// LDS 128KB: [buf][A 32K | B 32K], halves of 16KB. BK=64, NT=K/64 tiles.
template <int OUT_BF16>
__global__ __launch_bounds__(512, 2) void gemm_bt(const unsigned short* __restrict__ A,
                                                  const unsigned short* __restrict__ B,
                                                  void* __restrict__ Cout,
                                                  int M, int N, int K) {
  __shared__ __align__(16) char lds[131072];
  const int tid = threadIdx.x;
  const int lane = tid & 63, wave = tid >> 6;
  const int quad = lane >> 4, l16 = lane & 15;
  const int wave_m = wave >> 2, wave_n = wave & 3;
  const long row0 = (long)blockIdx.y * 256;
  const long col0 = (long)blockIdx.x * 256;
  const int NT = K >> 6;
  const long rowstride = (long)K * 2;

  f32x4 acc[8][4] = {};

  // stage one 16KB half-tile: operand base offset ob (0=A,32768=B), tile T,
  // half h, target buffer tbuf. 2 gl_lds per wave.
  auto stage = [&](const unsigned short* G, long base0, int ob, int T, int h, int tbuf) {
    if (T >= NT) return;
    char* dst = lds + tbuf * 65536 + ob + h * 16384 + wave * 1024;
    const char* src = (const char*)G + (base0 + h * 128) * rowstride + (long)T * 128;
#pragma unroll
    for (int c = 0; c < 2; ++c) {
      int b = c * 8192 + wave * 1024 + lane * 16;
      int r = b >> 7, cb = b & 127;
      gl_lds16(src + (long)r * rowstride + (cb ^ swz(r)), dst + c * 8192);
    }
  };

#define STAGE_A(T, h, tbuf) stage(A, row0, 0, (T), (h), (tbuf))
#define STAGE_B(T, h, tbuf) stage(B, col0, 32768, (T), (h), (tbuf))

  // prologue: T0 fully + T1 Ah0,Bh0; vmcnt(4) leaves only T1's 2 halves open
  STAGE_A(0, 0, 0); STAGE_B(0, 0, 0); STAGE_A(0, 1, 0); STAGE_B(0, 1, 0);
  STAGE_A(1, 0, 1); STAGE_B(1, 0, 1);
  asm volatile("s_waitcnt vmcnt(4)" ::: "memory");
  barrier_np();

  for (int g = 0; g < NT; ++g) {
    const int buf = g & 1;
    const char* Ab = lds + buf * 65536;
    const char* Bb = lds + buf * 65536 + 32768;

#define PHASE(MH, NH, STAGE_STMT, FENCE_STMT)                                   \
    {                                                                           \
      bf16x8 a[2][4], b[2][2];                                                  \
      {                                                                         \
        const char* base = Ab + (MH) * 16384;                                   \
        _Pragma("unroll")                                                       \
        for (int mi = 0; mi < 4; ++mi) {                                        \
          int r = wave_m * 64 + mi * 16 + l16;                                  \
          const char* rp = base + r * 128;                                      \
          int sw = swz(r);                                                      \
          a[0][mi] = *(const bf16x8*)(rp + ((quad * 16) ^ sw));                 \
          a[1][mi] = *(const bf16x8*)(rp + ((64 + quad * 16) ^ sw));            \
        }                                                                       \
      }                                                                         \
      {                                                                         \
        const char* base = Bb + (NH) * 16384;                                   \
        _Pragma("unroll")                                                       \
        for (int ni = 0; ni < 2; ++ni) {                                        \
          int r = wave_n * 32 + ni * 16 + l16;                                  \
          const char* rp = base + r * 128;                                      \
          int sw = swz(r);                                                      \
          b[0][ni] = *(const bf16x8*)(rp + ((quad * 16) ^ sw));                 \
          b[1][ni] = *(const bf16x8*)(rp + ((64 + quad * 16) ^ sw));            \
        }                                                                       \
      }                                                                         \
      STAGE_STMT;                                                               \
      barrier_np();                                                             \
      asm volatile("s_waitcnt lgkmcnt(0)" ::: "memory");                        \
      __builtin_amdgcn_sched_barrier(0);                                        \
      __builtin_amdgcn_s_setprio(1);                                            \
      _Pragma("unroll")                                                         \
      for (int ks = 0; ks < 2; ++ks)                                            \
        _Pragma("unroll")                                                       \
        for (int mi = 0; mi < 4; ++mi)                                          \
          _Pragma("unroll")                                                     \
          for (int ni = 0; ni < 2; ++ni)                                        \
            acc[(MH) * 4 + mi][(NH) * 2 + ni] =                                 \
                __builtin_amdgcn_mfma_f32_16x16x32_bf16(                        \
                    a[ks][mi], b[ks][ni], acc[(MH) * 4 + mi][(NH) * 2 + ni],    \
                    0, 0, 0);                                                   \
      __builtin_amdgcn_s_setprio(0);                                            \
      FENCE_STMT;                                                               \
      barrier_np();                                                             \
    }

    PHASE(0, 0, STAGE_A(g + 1, 1, buf ^ 1), )
    PHASE(0, 1, STAGE_B(g + 1, 1, buf ^ 1), )
    PHASE(1, 0, STAGE_A(g + 2, 0, buf), )
    PHASE(1, 1, STAGE_B(g + 2, 0, buf),
          if (g + 2 < NT) { asm volatile("s_waitcnt vmcnt(4)" ::: "memory"); }
          else            { asm volatile("s_waitcnt vmcnt(0)" ::: "memory"); })
#undef PHASE
  }
#undef STAGE_A
#undef STAGE_B

  // epilogue: C write (C/D layout: col=l16, row=quad*4+r per 16x16 frag)
#pragma unroll
  for (int mi = 0; mi < 8; ++mi) {
    const int mh = mi >> 2, mq = mi & 3;
#pragma unroll
    for (int ni = 0; ni < 4; ++ni) {
      const int nh = ni >> 1, nq = ni & 1;
#pragma unroll
      for (int r = 0; r < 4; ++r) {
        long row = row0 + mh * 128 + wave_m * 64 + mq * 16 + quad * 4 + r;
        long col = col0 + nh * 128 + wave_n * 32 + nq * 16 + l16;
        float v = acc[mi][ni][r];
        if (OUT_BF16) ((unsigned short*)Cout)[row * N + col] = f2b(v);
        else          ((float*)Cout)[row * N + col] = v;
      }
    }
  }
}

// ------------------------------------------- RoPE + sym int8 quant-dequant + split
// qkv[2048][6144] bf16 -> Qb[32][2048][128], Kb[8][2048][128], Vb[8][2048][128]
__global__ __launch_bounds__(256) void postproc(const unsigned short* __restrict__ qkv,
                                                const int* __restrict__ pos_ids,
                                                unsigned short* __restrict__ Qb,
                                                unsigned short* __restrict__ Kb,
                                                unsigned short* __restrict__ Vb) {
  const int s = blockIdx.x;
  const int lane = threadIdx.x & 63, wave = threadIdx.x >> 6;
  const float pos = (float)pos_ids[s];
  // inv_freq = 10000^(-lane/64) = exp(-lane * ln(10000)/64); pair (d, d+64)
  const float invf = expf(-(float)lane * 0.14391156831212787f);
  const float ang = pos * invf;
  const float ca = cosf(ang), sa = sinf(ang);

  for (int r = wave; r < 48; r += 4) {
    if (r < 32) {                 // Q head r: rope only
      const unsigned short* src = qkv + (long)s * QKV_N + r * HD;
      float x0 = b2f(src[lane]), x1 = b2f(src[lane + 64]);
      unsigned short* dst = Qb + ((long)r * S_LEN + s) * HD;
      dst[lane]      = f2b(x0 * ca - x1 * sa);
      dst[lane + 64] = f2b(x1 * ca + x0 * sa);
    } else if (r < 40) {          // K head r-32: rope then quant-dequant
      int h = r - 32;
      const unsigned short* src = qkv + (long)s * QKV_N + 4096 + h * HD;
      float x0 = b2f(src[lane]), x1 = b2f(src[lane + 64]);
      float y0 = x0 * ca - x1 * sa;
      float y1 = x1 * ca + x0 * sa;
      float m = fmaxf(fabsf(y0), fabsf(y1));
      for (int off = 32; off; off >>= 1) m = fmaxf(m, __shfl_xor(m, off, 64));
      float scale = fmaxf(m / 127.0f, 1e-9f);
      float q0 = fminf(fmaxf(rintf(y0 / scale), -128.f), 127.f);
      float q1 = fminf(fmaxf(rintf(y1 / scale), -128.f), 127.f);
      unsigned short* dst = Kb + ((long)h * S_LEN + s) * HD;
      dst[lane]      = f2b(q0 * scale);
      dst[lane + 64] = f2b(q1 * scale);
    } else {                      // V head r-40: quant-dequant only
      int h = r - 40;
      const unsigned short* src = qkv + (long)s * QKV_N + 5120 + h * HD;
      float x0 = b2f(src[lane]), x1 = b2f(src[lane + 64]);
      float m = fmaxf(fabsf(x0), fabsf(x1));
      for (int off = 32; off; off >>= 1) m = fmaxf(m, __shfl_xor(m, off, 64));
      float scale = fmaxf(m / 127.0f, 1e-9f);
      float q0 = fminf(fmaxf(rintf(x0 / scale), -128.f), 127.f);
      float q1 = fminf(fmaxf(rintf(x1 / scale), -128.f), 127.f);
      unsigned short* dst = Vb + ((long)h * S_LEN + s) * HD;
      dst[lane]      = f2b(q0 * scale);
      dst[lane + 64] = f2b(q1 * scale);
    }
  }
}

// -------------------------------------------------- V transpose: [h][s][d]->[h][d][s]
__global__ __launch_bounds__(256) void transpose_v(const unsigned short* __restrict__ Vb,
                                                   unsigned short* __restrict__ Vtb) {
  __shared__ unsigned short t[64][136];
  const int h = blockIdx.x >> 5, st = blockIdx.x & 31;
  const int tid = threadIdx.x;
  const long vbase = (long)h * S_LEN * HD;
#pragma unroll
  for (int p = 0; p < 8; ++p) {
    int e = p * 1024 + tid * 4;
    int sl = e >> 7, d = e & 127;
    ushort4 v = *(const ushort4*)(Vb + vbase + (long)(st * 64 + sl) * HD + d);
    t[sl][d] = v.x; t[sl][d + 1] = v.y; t[sl][d + 2] = v.z; t[sl][d + 3] = v.w;
  }
  __syncthreads();
  const long tbase = (long)h * HD * S_LEN;
#pragma unroll
  for (int p = 0; p < 8; ++p) {
    int o = p * 1024 + tid * 4;
    int d = o >> 6, sl = o & 63;
    ushort4 v;
    v.x = t[sl][d]; v.y = t[sl + 1][d]; v.z = t[sl + 2][d]; v.w = t[sl + 3][d];
    *(ushort4*)(Vtb + tbase + (long)d * S_LEN + st * 64 + sl) = v;
  }
}

// ------------------------------------------------------------- flash attention
// Block = (head, 128-row q-tile), 4 waves x 32 q-rows. KVBLK=64.
// K tile [64 keys][128 d] and Vt tile [128 d][64 keys] staged in LDS via
// global_load_lds (shared by all waves), double-buffered 2-phase:
//   barrier(drains prev stage) -> issue stage(t+1) -> compute(t).
// XOR swizzle on K/Vt/Ps rows applied on BOTH the pre-swizzled global source
// (linear LDS dest, rule #21) and the ds_read/ds_write side -> conflict-free.
// LDS: K 2x16K + Vt 2x16K + Ps 16K = 80 KB exactly -> 2 blocks/CU.
// Complementary qt pairing: steps/pair = (2qt+2)+(2(15-qt)+2) = 34, balanced.
__global__ __launch_bounds__(256, 2) void attn_kernel(const unsigned short* __restrict__ Qb,
                                                      const unsigned short* __restrict__ Kb,
                                                      const unsigned short* __restrict__ Vtb,
                                                      unsigned short* __restrict__ Ob) {
  __shared__ __align__(16) char lds[81920];
  // layout: K buf0 @0, K buf1 @16384, V buf0 @32768, V buf1 @49152, Ps @65536

  const int bx = blockIdx.x;
  const int p8 = bx & 1;
  const int g = (bx >> 1) & 7;
  const int b8 = bx >> 8;
  const int qt = (p8 ^ b8) ? (15 - g) : g;
  const int h = ((bx >> 4) & 15) + 16 * b8;
  const int hk = h >> 2;                        // GQA: 4 q-heads per kv-head
  const int tid = threadIdx.x;
  const int lane = tid & 63, wave = tid >> 6;
  const int quad = lane >> 4, l16 = lane & 15;

  // Q fragments for this wave's 32 rows (A-operand layout), from global
  bf16x8 qf[2][4];
  {
    const unsigned short* qb =
        Qb + ((long)h * S_LEN + qt * 128 + wave * 32 + l16) * HD + quad * 8;
#pragma unroll
    for (int mi = 0; mi < 2; ++mi)
#pragma unroll
      for (int ks = 0; ks < 4; ++ks)
        qf[mi][ks] = *(const bf16x8*)(qb + mi * 16 * HD + ks * 32);
  }

  f32x4 O[2][8] = {};
  float mrow[2][4], lrow[2][4];
#pragma unroll
  for (int mi = 0; mi < 2; ++mi)
#pragma unroll
    for (int r = 0; r < 4; ++r) { mrow[mi][r] = -1e30f; lrow[mi][r] = 0.f; }

  const char* Kg = (const char*)(Kb + (long)hk * S_LEN * HD);
  const char* Vg = (const char*)(Vtb + (long)hk * HD * S_LEN);
  char* PsB = lds + 65536;
  const float sscale = 0.08838834764831845f;  // 1/sqrt(128)
  const int nsteps = 2 * qt + 2;              // 64-key steps

  // stage one 64-key K tile (16 KB, contiguous rows in global) into buf
  auto stageK = [&](int step, int buf) {
    char* dst = lds + buf * 16384 + wave * 1024;
    const char* src = Kg + (long)step * 16384;
#pragma unroll
    for (int c = 0; c < 4; ++c) {
      int f = c * 4096 + tid * 16;
      int row = f >> 8, wb = f & 255;
      gl_lds16(src + row * 256 + (wb ^ swz(row)), dst + c * 4096);
    }
  };
  // stage one Vt tile [128 d][64 keys] (d-rows strided 4096B in global)
  auto stageV = [&](int step, int buf) {
    char* dst = lds + 32768 + buf * 16384 + wave * 1024;
    const char* src = Vg + (long)step * 128;
#pragma unroll
    for (int c = 0; c < 4; ++c) {
      int f = c * 4096 + tid * 16;
      int d = f >> 7, wb = f & 127;
      gl_lds16(src + (long)d * (S_LEN * 2) + (wb ^ swz(d)), dst + c * 4096);
    }
  };

  stageK(0, 0);
  stageV(0, 0);

  for (int t = 0; t < nsteps; ++t) {
    __syncthreads();   // drains this wave's stage (vmcnt 0) + syncs all waves
    if (t + 1 < nsteps) {
      stageK(t + 1, (t + 1) & 1);
      stageV(t + 1, (t + 1) & 1);
    }
    const char* Ks = lds + (t & 1) * 16384;
    const char* Vs = lds + 32768 + (t & 1) * 16384;

    // ---- S = Q K^T over 64 keys (4 ni of 16)
    f32x4 S[2][4] = {};
    __builtin_amdgcn_s_setprio(1);
#pragma unroll
    for (int ni = 0; ni < 4; ++ni) {
      const int row = ni * 16 + l16;
      const char* kr = Ks + row * 256;
      const int sw = swz(row);
      const int q16 = quad * 16;
      bf16x8 kf0 = *(const bf16x8*)(kr + ((q16 + 0)   ^ sw));
      bf16x8 kf1 = *(const bf16x8*)(kr + ((q16 + 64)  ^ sw));
      bf16x8 kf2 = *(const bf16x8*)(kr + ((q16 + 128) ^ sw));
      bf16x8 kf3 = *(const bf16x8*)(kr + ((q16 + 192) ^ sw));
      S[0][ni] = __builtin_amdgcn_mfma_f32_16x16x32_bf16(qf[0][0], kf0, S[0][ni], 0, 0, 0);
      S[1][ni] = __builtin_amdgcn_mfma_f32_16x16x32_bf16(qf[1][0], kf0, S[1][ni], 0, 0, 0);
      S[0][ni] = __builtin_amdgcn_mfma_f32_16x16x32_bf16(qf[0][1], kf1, S[0][ni], 0, 0, 0);
      S[1][ni] = __builtin_amdgcn_mfma_f32_16x16x32_bf16(qf[1][1], kf1, S[1][ni], 0, 0, 0);
      S[0][ni] = __builtin_amdgcn_mfma_f32_16x16x32_bf16(qf[0][2], kf2, S[0][ni], 0, 0, 0);
      S[1][ni] = __builtin_amdgcn_mfma_f32_16x16x32_bf16(qf[1][2], kf2, S[1][ni], 0, 0, 0);
      S[0][ni] = __builtin_amdgcn_mfma_f32_16x16x32_bf16(qf[0][3], kf3, S[0][ni], 0, 0, 0);
      S[1][ni] = __builtin_amdgcn_mfma_f32_16x16x32_bf16(qf[1][3], kf3, S[1][ni], 0, 0, 0);
    }
    __builtin_amdgcn_s_setprio(0);

    // ---- scale + causal mask + row max
    const bool diag = (t >= 2 * qt);
    const int qrow_base = qt * 128 + wave * 32;
    float rmax[2][4];
#pragma unroll
    for (int mi = 0; mi < 2; ++mi)
#pragma unroll
      for (int r = 0; r < 4; ++r) rmax[mi][r] = -1e30f;
#pragma unroll
    for (int mi = 0; mi < 2; ++mi)
#pragma unroll
      for (int ni = 0; ni < 4; ++ni) {
        int col = t * 64 + ni * 16 + l16;
#pragma unroll
        for (int r = 0; r < 4; ++r) {
          int row = qrow_base + mi * 16 + quad * 4 + r;
          float v = S[mi][ni][r] * sscale;
          if (diag && col > row) v = -1e9f;
          S[mi][ni][r] = v;
          rmax[mi][r] = fmaxf(rmax[mi][r], v);
        }
      }
    float alpha[2][4], rsum[2][4];
#pragma unroll
    for (int mi = 0; mi < 2; ++mi)
#pragma unroll
      for (int r = 0; r < 4; ++r) {
        float v = rmax[mi][r];
        v = fmaxf(v, __shfl_xor(v, 1, 64));
        v = fmaxf(v, __shfl_xor(v, 2, 64));
        v = fmaxf(v, __shfl_xor(v, 4, 64));
        v = fmaxf(v, __shfl_xor(v, 8, 64));
        float mnew = fmaxf(mrow[mi][r], v);
        alpha[mi][r] = __expf(mrow[mi][r] - mnew);
        mrow[mi][r] = mnew;
        rsum[mi][r] = 0.f;
      }

    // ---- P = exp(S - m) -> wave-local swizzled LDS rows, accumulate sums
#pragma unroll
    for (int mi = 0; mi < 2; ++mi)
#pragma unroll
      for (int ni = 0; ni < 4; ++ni)
#pragma unroll
        for (int r = 0; r < 4; ++r) {
          float p = __expf(S[mi][ni][r] - mrow[mi][r]);
          rsum[mi][r] += p;
          int prow = wave * 32 + mi * 16 + quad * 4 + r;
          int pcol2 = (ni * 16 + l16) * 2;
          *(unsigned short*)(PsB + prow * 128 + (pcol2 ^ swz(prow))) = f2b(p);
        }
#pragma unroll
    for (int mi = 0; mi < 2; ++mi)
#pragma unroll
      for (int r = 0; r < 4; ++r) {
        float v = rsum[mi][r];
        v += __shfl_xor(v, 1, 64);
        v += __shfl_xor(v, 2, 64);
        v += __shfl_xor(v, 4, 64);
        v += __shfl_xor(v, 8, 64);
        lrow[mi][r] = lrow[mi][r] * alpha[mi][r] + v;
      }
#pragma unroll
    for (int mi = 0; mi < 2; ++mi)
#pragma unroll
      for (int ni = 0; ni < 8; ++ni)
#pragma unroll
        for (int r = 0; r < 4; ++r) O[mi][ni][r] *= alpha[mi][r];

    // ---- O += P V : P A-frags from wave-local LDS, Vt B-frags from LDS tile
    bf16x8 pf[2][2];
#pragma unroll
    for (int mi = 0; mi < 2; ++mi)
#pragma unroll
      for (int ks2 = 0; ks2 < 2; ++ks2) {
        int prow = wave * 32 + mi * 16 + l16;
        pf[mi][ks2] = *(const bf16x8*)(PsB + prow * 128 +
                                       ((ks2 * 64 + quad * 16) ^ swz(prow)));
      }
    __builtin_amdgcn_s_setprio(1);
#pragma unroll
    for (int ni = 0; ni < 8; ++ni) {
      const int row = ni * 16 + l16;
      const char* vr = Vs + row * 128;
      const int sw = swz(row);
      const int q16 = quad * 16;
      bf16x8 vf0 = *(const bf16x8*)(vr + ((q16 + 0)  ^ sw));
      bf16x8 vf1 = *(const bf16x8*)(vr + ((q16 + 64) ^ sw));
      O[0][ni] = __builtin_amdgcn_mfma_f32_16x16x32_bf16(pf[0][0], vf0, O[0][ni], 0, 0, 0);
      O[1][ni] = __builtin_amdgcn_mfma_f32_16x16x32_bf16(pf[1][0], vf0, O[1][ni], 0, 0, 0);
      O[0][ni] = __builtin_amdgcn_mfma_f32_16x16x32_bf16(pf[0][1], vf1, O[0][ni], 0, 0, 0);
      O[1][ni] = __builtin_amdgcn_mfma_f32_16x16x32_bf16(pf[1][1], vf1, O[1][ni], 0, 0, 0);
    }
    __builtin_amdgcn_s_setprio(0);
  }

  // normalize + store bf16 at [s][h*128+d]
#pragma unroll
  for (int mi = 0; mi < 2; ++mi)
#pragma unroll
    for (int r = 0; r < 4; ++r) {
      float inv = 1.0f / lrow[mi][r];
      long srow = qt * 128 + wave * 32 + mi * 16 + quad * 4 + r;
#pragma unroll
      for (int ni = 0; ni < 8; ++ni) {
        long col = (long)h * HD + ni * 16 + l16;
        Ob[srow * (long)HID + col] = f2b(O[mi][ni][r] * inv);
      }
    }
}

// ---------------------------------------------------------------------------
extern "C" void kernel_launch(void* const* d_in, const int* in_sizes, int n_in,
                              void* d_out, int out_size, void* d_ws, size_t ws_size,
                              hipStream_t stream) {
  const float* hidden = (const float*)d_in[0];
  const float* wq = (const float*)d_in[1];
  const float* wk = (const float*)d_in[2];
  const float* wv = (const float*)d_in[3];
  const float* wo = (const float*)d_in[4];
  const int* pos = (const int*)d_in[5];
  float* out = (float*)d_out;

  // workspace layout (bytes); total 138,412,032. Overlays: Qb=hid_b (hid dead
  // after GEMM1), attn_b=qkv_b (qkv dead after postproc).
  char* ws = (char*)d_ws;
  unsigned short* wqkv_b = (unsigned short*)(ws);               // 50,331,648
  unsigned short* wo_b   = (unsigned short*)(ws + 50331648);    // 33,554,432
  unsigned short* hid_b  = (unsigned short*)(ws + 83886080);    // 16,777,216
  unsigned short* qkv_b  = (unsigned short*)(ws + 100663296);   // 25,165,824
  unsigned short* Kb     = (unsigned short*)(ws + 125829120);   //  4,194,304
  unsigned short* Vb     = (unsigned short*)(ws + 130023424);   //  4,194,304
  unsigned short* Vtb    = (unsigned short*)(ws + 134217728);   //  4,194,304
  unsigned short* Qb     = hid_b;
  unsigned short* attn_b = qkv_b;

  cast_kernel<<<8388608 / 1024, 256, 0, stream>>>(hidden, hid_b, 8388608 / 4);
  cast_kernel<<<16777216 / 1024, 256, 0, stream>>>(wq, wqkv_b, 16777216 / 4);
  cast_kernel<<<4194304 / 1024, 256, 0, stream>>>(wk, wqkv_b + 16777216, 4194304 / 4);
  cast_kernel<<<4194304 / 1024, 256, 0, stream>>>(wv, wqkv_b + 20971520, 4194304 / 4);
  cast_kernel<<<16777216 / 1024, 256, 0, stream>>>(wo, wo_b, 16777216 / 4);

  gemm_bt<1><<<dim3(QKV_N / 256, S_LEN / 256), 512, 0, stream>>>(
      hid_b, wqkv_b, (void*)qkv_b, S_LEN, QKV_N, HID);

  postproc<<<S_LEN, 256, 0, stream>>>(qkv_b, pos, Qb, Kb, Vb);
  transpose_v<<<NKV * 32, 256, 0, stream>>>(Vb, Vtb);
  attn_kernel<<<NH * 16, 256, 0, stream>>>(Qb, Kb, Vtb, attn_b);

  gemm_bt<0><<<dim3(HID / 256, S_LEN / 256), 512, 0, stream>>>(
      attn_b, wo_b, (void*)out, S_LEN, HID, HID);
}

// Round 3
// 551.512 us; speedup vs baseline: 1.0661x; 1.0661x over previous
//
#include <hip/hip_runtime.h>

// ---------------------------------------------------------------------------
// LlamaAttention_Tender: hidden(2048x4096) -> QKV proj -> RoPE -> int8 qdq(K,V)
// -> GQA causal attention (32 q-heads, 8 kv-heads, D=128) -> out proj.
// R5: 8-phase GEMM inner loop made compiler-opaque: ds_read_b128 via inline
//     asm (no alias info -> no auto vmcnt(0) drains), explicit lgkmcnt(0) +
//     sched_barrier(0) (rule #18), counted vmcnt(4) remains the ONLY VMEM
//     fence in the loop. A/B half-fragments cached in regs across phase
//     pairs (24 ds_reads/tile instead of 48).
// ---------------------------------------------------------------------------

#define S_LEN 2048
#define HID 4096
#define NH 32
#define NKV 8
#define HD 128
#define QKV_N 6144   // 4096 q + 1024 k + 1024 v

typedef __bf16 bf16x8 __attribute__((ext_vector_type(8)));
typedef float f32x4 __attribute__((ext_vector_type(4)));

__device__ __forceinline__ unsigned short f2b(float f) {
  unsigned int u = __float_as_uint(f);
  u += 0x7fffu + ((u >> 16) & 1u);   // round-to-nearest-even
  return (unsigned short)(u >> 16);
}
__device__ __forceinline__ float b2f(unsigned short h) {
  return __uint_as_float(((unsigned int)h) << 16);
}
// async global->LDS, 16B per lane. LDS dst must be wave-uniform (lane*16 implicit).
__device__ __forceinline__ void gl_lds16(const void* g, void* l) {
  __builtin_amdgcn_global_load_lds(
      (__attribute__((address_space(1))) void*)g,
      (__attribute__((address_space(3))) void*)l, 16, 0, 0);
}
// compiler-opaque LDS b128 read: no alias info, so no auto-inserted vmcnt
// waits against in-flight global_load_lds prefetches. Ordering enforced
// manually via s_waitcnt lgkmcnt + sched_barrier at the use point.
__device__ __forceinline__ bf16x8 ds_read128(const void* p) {
  bf16x8 r;
  unsigned a = (unsigned)(unsigned long long)
      (__attribute__((address_space(3))) const void*)p;
  asm volatile("ds_read_b128 %0, %1" : "=v"(r) : "v"(a));
  return r;
}
// LDS bank-spread swizzle: permutes 16B chunks within a 128B row; involution.
__device__ __forceinline__ int swz(int row) {
  return ((row & 7) << 4) ^ (((row >> 3) & 1) << 5);
}
// barrier without the __syncthreads vmcnt(0) drain; asm fences stop IR motion
__device__ __forceinline__ void barrier_np() {
  asm volatile("" ::: "memory");
  __builtin_amdgcn_s_barrier();
  asm volatile("" ::: "memory");
}

// ---------------------------------------------------------------- cast fp32->bf16
__global__ __launch_bounds__(256) void cast_kernel(const float* __restrict__ src,
                                                   unsigned short* __restrict__ dst,
                                                   int n4) {
  int i = blockIdx.x * 256 + threadIdx.x;
  if (i >= n4) return;
  float4 v = ((const float4*)src)[i];
  ushort4 o;
  o.x = f2b(v.x); o.y = f2b(v.y); o.z = f2b(v.z); o.w = f2b(v.w);
  ((ushort4*)dst)[i] = o;
}

// --------------------------------------------- B^T GEMM, 256x256 8-phase template
// C[M,N] = A[M,K]*B[N,K]^T. 512 thr = 8 waves (2Mx4N), per-wave out 128x64
// (rows: mh*128 + wave_m*64 + mi*16, cols: nh*128 + wave_n*32 + ni*16).
// LDS 128KB: [buf][A 32K | B 32K], halves of 16KB. BK=64, NT=K/64 tiles.
// Phases: p1 reads A0+B0 (12 asm ds_reads), p2 B1 (4), p3 A1 (8), p4 none;
// b0/b1 reg-cached across the pair. Stage: p1:Ah1(T+1) p2:Bh1(T+1)
// p3:Ah0(T+2) p4:Bh0(T+2); fence vmcnt(4) only at p4 (0 in the 2-group tail).
template <int OUT_BF16>
__global__ __launch_bounds__(512, 2) void gemm_bt(const unsigned short* __restrict__ A,
                                                  const unsigned short* __restrict__ B,
                                                  void* __restrict__ Cout,
                                                  int M, int N, int K) {
  __shared__ __align__(16) char lds[131072];
  const int tid = threadIdx.x;
  const int lane = tid & 63, wave = tid >> 6;
  const int quad = lane >> 4, l16 = lane & 15;
  const int wave_m = wave >> 2, wave_n = wave & 3;
  const long row0 = (long)blockIdx.y * 256;
  const long col0 = (long)blockIdx.x * 256;
  const int NT = K >> 6;
  const long rowstride = (long)K * 2;

  f32x4 acc[8][4] = {};

  // stage one 16KB half-tile: operand base offset ob (0=A,32768=B), tile T,
  // half h, target buffer tbuf. 2 gl_lds per wave.
  auto stage = [&](const unsigned short* G, long base0, int ob, int T, int h, int tbuf) {
    if (T >= NT) return;
    char* dst = lds + tbuf * 65536 + ob + h * 16384 + wave * 1024;
    const char* src = (const char*)G + (base0 + h * 128) * rowstride + (long)T * 128;
#pragma unroll
    for (int c = 0; c < 2; ++c) {
      int b = c * 8192 + wave * 1024 + lane * 16;
      int r = b >> 7, cb = b & 127;
      gl_lds16(src + (long)r * rowstride + (cb ^ swz(r)), dst + c * 8192);
    }
  };

#define STAGE_A(T, h, tbuf) stage(A, row0, 0, (T), (h), (tbuf))
#define STAGE_B(T, h, tbuf) stage(B, col0, 32768, (T), (h), (tbuf))

  // A-half (8 reads) / B-half (4 reads) register loads, swizzled addresses
  auto readA = [&](const char* base, bf16x8 (&a)[2][4]) {
#pragma unroll
    for (int mi = 0; mi < 4; ++mi) {
      int r = wave_m * 64 + mi * 16 + l16;
      const char* rp = base + r * 128;
      int sw = swz(r);
      a[0][mi] = ds_read128(rp + ((quad * 16) ^ sw));
      a[1][mi] = ds_read128(rp + ((64 + quad * 16) ^ sw));
    }
  };
  auto readB = [&](const char* base, bf16x8 (&b)[2][2]) {
#pragma unroll
    for (int ni = 0; ni < 2; ++ni) {
      int r = wave_n * 32 + ni * 16 + l16;
      const char* rp = base + r * 128;
      int sw = swz(r);
      b[0][ni] = ds_read128(rp + ((quad * 16) ^ sw));
      b[1][ni] = ds_read128(rp + ((64 + quad * 16) ^ sw));
    }
  };

#define WAITL0                                            \
  do {                                                    \
    asm volatile("s_waitcnt lgkmcnt(0)" ::: "memory");    \
    __builtin_amdgcn_sched_barrier(0);                    \
  } while (0)

#define MFMA_BLOCK(MH, NHh, A_, B_)                                          \
  do {                                                                       \
    __builtin_amdgcn_s_setprio(1);                                           \
    _Pragma("unroll")                                                        \
    for (int ks = 0; ks < 2; ++ks)                                           \
      _Pragma("unroll")                                                      \
      for (int mi = 0; mi < 4; ++mi)                                         \
        _Pragma("unroll")                                                    \
        for (int ni = 0; ni < 2; ++ni)                                       \
          acc[(MH) * 4 + mi][(NHh) * 2 + ni] =                               \
              __builtin_amdgcn_mfma_f32_16x16x32_bf16(                       \
                  A_[ks][mi], B_[ks][ni],                                    \
                  acc[(MH) * 4 + mi][(NHh) * 2 + ni], 0, 0, 0);              \
    __builtin_amdgcn_s_setprio(0);                                           \
  } while (0)

  // prologue: T0 fully + T1 Ah0,Bh0; vmcnt(4) leaves only T1's h0 halves open
  STAGE_A(0, 0, 0); STAGE_B(0, 0, 0); STAGE_A(0, 1, 0); STAGE_B(0, 1, 0);
  STAGE_A(1, 0, 1); STAGE_B(1, 0, 1);
  asm volatile("s_waitcnt vmcnt(4)" ::: "memory");
  barrier_np();

  for (int g = 0; g < NT; ++g) {
    const int buf = g & 1;
    const char* Ab = lds + buf * 65536;
    const char* Bb = Ab + 32768;
    bf16x8 a[2][4], b0[2][2], b1[2][2];

    // ---- phase 1: A0+B0 -> MFMA quadrant (0,0); stage Ah1(T+1)
    readA(Ab, a);
    readB(Bb, b0);
    STAGE_A(g + 1, 1, buf ^ 1);
    barrier_np();
    WAITL0;
    MFMA_BLOCK(0, 0, a, b0);
    barrier_np();

    // ---- phase 2: B1 (A0 reg-cached) -> (0,1); stage Bh1(T+1)
    readB(Bb + 16384, b1);
    STAGE_B(g + 1, 1, buf ^ 1);
    barrier_np();
    WAITL0;
    MFMA_BLOCK(0, 1, a, b1);
    barrier_np();

    // ---- phase 3: A1 (B0 reg-cached) -> (1,0); stage Ah0(T+2)
    readA(Ab + 16384, a);
    STAGE_A(g + 2, 0, buf);
    barrier_np();
    WAITL0;
    MFMA_BLOCK(1, 0, a, b0);
    barrier_np();

    // ---- phase 4: all reg-cached -> (1,1); stage Bh0(T+2); counted fence
    STAGE_B(g + 2, 0, buf);
    barrier_np();
    WAITL0;
    MFMA_BLOCK(1, 1, a, b1);
    if (g + 2 < NT) { asm volatile("s_waitcnt vmcnt(4)" ::: "memory"); }
    else            { asm volatile("s_waitcnt vmcnt(0)" ::: "memory"); }
    barrier_np();
  }
#undef STAGE_A
#undef STAGE_B
#undef WAITL0
#undef MFMA_BLOCK

  // epilogue: C write (C/D layout: col=l16, row=quad*4+r per 16x16 frag)
#pragma unroll
  for (int mi = 0; mi < 8; ++mi) {
    const int mh = mi >> 2, mq = mi & 3;
#pragma unroll
    for (int ni = 0; ni < 4; ++ni) {
      const int nh = ni >> 1, nq = ni & 1;
#pragma unroll
      for (int r = 0; r < 4; ++r) {
        long row = row0 + mh * 128 + wave_m * 64 + mq * 16 + quad * 4 + r;
        long col = col0 + nh * 128 + wave_n * 32 + nq * 16 + l16;
        float v = acc[mi][ni][r];
        if (OUT_BF16) ((unsigned short*)Cout)[row * N + col] = f2b(v);
        else          ((float*)Cout)[row * N + col] = v;
      }
    }
  }
}

// ------------------------------------------- RoPE + sym int8 quant-dequant + split
// qkv[2048][6144] bf16 -> Qb[32][2048][128], Kb[8][2048][128], Vb[8][2048][128]
__global__ __launch_bounds__(256) void postproc(const unsigned short* __restrict__ qkv,
                                                const int* __restrict__ pos_ids,
                                                unsigned short* __restrict__ Qb,
                                                unsigned short* __restrict__ Kb,
                                                unsigned short* __restrict__ Vb) {
  const int s = blockIdx.x;
  const int lane = threadIdx.x & 63, wave = threadIdx.x >> 6;
  const float pos = (float)pos_ids[s];
  // inv_freq = 10000^(-lane/64) = exp(-lane * ln(10000)/64); pair (d, d+64)
  const float invf = expf(-(float)lane * 0.14391156831212787f);
  const float ang = pos * invf;
  const float ca = cosf(ang), sa = sinf(ang);

  for (int r = wave; r < 48; r += 4) {
    if (r < 32) {                 // Q head r: rope only
      const unsigned short* src = qkv + (long)s * QKV_N + r * HD;
      float x0 = b2f(src[lane]), x1 = b2f(src[lane + 64]);
      unsigned short* dst = Qb + ((long)r * S_LEN + s) * HD;
      dst[lane]      = f2b(x0 * ca - x1 * sa);
      dst[lane + 64] = f2b(x1 * ca + x0 * sa);
    } else if (r < 40) {          // K head r-32: rope then quant-dequant
      int h = r - 32;
      const unsigned short* src = qkv + (long)s * QKV_N + 4096 + h * HD;
      float x0 = b2f(src[lane]), x1 = b2f(src[lane + 64]);
      float y0 = x0 * ca - x1 * sa;
      float y1 = x1 * ca + x0 * sa;
      float m = fmaxf(fabsf(y0), fabsf(y1));
      for (int off = 32; off; off >>= 1) m = fmaxf(m, __shfl_xor(m, off, 64));
      float scale = fmaxf(m / 127.0f, 1e-9f);
      float q0 = fminf(fmaxf(rintf(y0 / scale), -128.f), 127.f);
      float q1 = fminf(fmaxf(rintf(y1 / scale), -128.f), 127.f);
      unsigned short* dst = Kb + ((long)h * S_LEN + s) * HD;
      dst[lane]      = f2b(q0 * scale);
      dst[lane + 64] = f2b(q1 * scale);
    } else {                      // V head r-40: quant-dequant only
      int h = r - 40;
      const unsigned short* src = qkv + (long)s * QKV_N + 5120 + h * HD;
      float x0 = b2f(src[lane]), x1 = b2f(src[lane + 64]);
      float m = fmaxf(fabsf(x0), fabsf(x1));
      for (int off = 32; off; off >>= 1) m = fmaxf(m, __shfl_xor(m, off, 64));
      float scale = fmaxf(m / 127.0f, 1e-9f);
      float q0 = fminf(fmaxf(rintf(x0 / scale), -128.f), 127.f);
      float q1 = fminf(fmaxf(rintf(x1 / scale), -128.f), 127.f);
      unsigned short* dst = Vb + ((long)h * S_LEN + s) * HD;
      dst[lane]      = f2b(q0 * scale);
      dst[lane + 64] = f2b(q1 * scale);
    }
  }
}

// -------------------------------------------------- V transpose: [h][s][d]->[h][d][s]
__global__ __launch_bounds__(256) void transpose_v(const unsigned short* __restrict__ Vb,
                                                   unsigned short* __restrict__ Vtb) {
  __shared__ unsigned short t[64][136];
  const int h = blockIdx.x >> 5, st = blockIdx.x & 31;
  const int tid = threadIdx.x;
  const long vbase = (long)h * S_LEN * HD;
#pragma unroll
  for (int p = 0; p < 8; ++p) {
    int e = p * 1024 + tid * 4;
    int sl = e >> 7, d = e & 127;
    ushort4 v = *(const ushort4*)(Vb + vbase + (long)(st * 64 + sl) * HD + d);
    t[sl][d] = v.x; t[sl][d + 1] = v.y; t[sl][d + 2] = v.z; t[sl][d + 3] = v.w;
  }
  __syncthreads();
  const long tbase = (long)h * HD * S_LEN;
#pragma unroll
  for (int p = 0; p < 8; ++p) {
    int o = p * 1024 + tid * 4;
    int d = o >> 6, sl = o & 63;
    ushort4 v;
    v.x = t[sl][d]; v.y = t[sl + 1][d]; v.z = t[sl + 2][d]; v.w = t[sl + 3][d];
    *(ushort4*)(Vtb + tbase + (long)d * S_LEN + st * 64 + sl) = v;
  }
}

// ------------------------------------------------------------- flash attention
// Block = (head, 128-row q-tile), 4 waves x 32 q-rows. KVBLK=64.
// K tile [64 keys][128 d] and Vt tile [128 d][64 keys] staged in LDS via
// global_load_lds (shared by all waves), double-buffered 2-phase:
//   barrier(drains prev stage) -> issue stage(t+1) -> compute(t).
// XOR swizzle on K/Vt/Ps rows applied on BOTH the pre-swizzled global source
// (linear LDS dest, rule #21) and the ds_read/ds_write side -> conflict-free.
// LDS: K 2x16K + Vt 2x16K + Ps 16K = 80 KB exactly -> 2 blocks/CU.
// Complementary qt pairing: steps/pair = (2qt+2)+(2(15-qt)+2) = 34, balanced.
__global__ __launch_bounds__(256, 2) void attn_kernel(const unsigned short* __restrict__ Qb,
                                                      const unsigned short* __restrict__ Kb,
                                                      const unsigned short* __restrict__ Vtb,
                                                      unsigned short* __restrict__ Ob) {
  __shared__ __align__(16) char lds[81920];
  // layout: K buf0 @0, K buf1 @16384, V buf0 @32768, V buf1 @49152, Ps @65536

  const int bx = blockIdx.x;
  const int p8 = bx & 1;
  const int g = (bx >> 1) & 7;
  const int b8 = bx >> 8;
  const int qt = (p8 ^ b8) ? (15 - g) : g;
  const int h = ((bx >> 4) & 15) + 16 * b8;
  const int hk = h >> 2;                        // GQA: 4 q-heads per kv-head
  const int tid = threadIdx.x;
  const int lane = tid & 63, wave = tid >> 6;
  const int quad = lane >> 4, l16 = lane & 15;

  // Q fragments for this wave's 32 rows (A-operand layout), from global
  bf16x8 qf[2][4];
  {
    const unsigned short* qb =
        Qb + ((long)h * S_LEN + qt * 128 + wave * 32 + l16) * HD + quad * 8;
#pragma unroll
    for (int mi = 0; mi < 2; ++mi)
#pragma unroll
      for (int ks = 0; ks < 4; ++ks)
        qf[mi][ks] = *(const bf16x8*)(qb + mi * 16 * HD + ks * 32);
  }

  f32x4 O[2][8] = {};
  float mrow[2][4], lrow[2][4];
#pragma unroll
  for (int mi = 0; mi < 2; ++mi)
#pragma unroll
    for (int r = 0; r < 4; ++r) { mrow[mi][r] = -1e30f; lrow[mi][r] = 0.f; }

  const char* Kg = (const char*)(Kb + (long)hk * S_LEN * HD);
  const char* Vg = (const char*)(Vtb + (long)hk * HD * S_LEN);
  char* PsB = lds + 65536;
  const float sscale = 0.08838834764831845f;  // 1/sqrt(128)
  const int nsteps = 2 * qt + 2;              // 64-key steps

  // stage one 64-key K tile (16 KB, contiguous rows in global) into buf
  auto stageK = [&](int step, int buf) {
    char* dst = lds + buf * 16384 + wave * 1024;
    const char* src = Kg + (long)step * 16384;
#pragma unroll
    for (int c = 0; c < 4; ++c) {
      int f = c * 4096 + tid * 16;
      int row = f >> 8, wb = f & 255;
      gl_lds16(src + row * 256 + (wb ^ swz(row)), dst + c * 4096);
    }
  };
  // stage one Vt tile [128 d][64 keys] (d-rows strided 4096B in global)
  auto stageV = [&](int step, int buf) {
    char* dst = lds + 32768 + buf * 16384 + wave * 1024;
    const char* src = Vg + (long)step * 128;
#pragma unroll
    for (int c = 0; c < 4; ++c) {
      int f = c * 4096 + tid * 16;
      int d = f >> 7, wb = f & 127;
      gl_lds16(src + (long)d * (S_LEN * 2) + (wb ^ swz(d)), dst + c * 4096);
    }
  };

  stageK(0, 0);
  stageV(0, 0);

  for (int t = 0; t < nsteps; ++t) {
    __syncthreads();   // drains this wave's stage (vmcnt 0) + syncs all waves
    if (t + 1 < nsteps) {
      stageK(t + 1, (t + 1) & 1);
      stageV(t + 1, (t + 1) & 1);
    }
    const char* Ks = lds + (t & 1) * 16384;
    const char* Vs = lds + 32768 + (t & 1) * 16384;

    // ---- S = Q K^T over 64 keys (4 ni of 16)
    f32x4 S[2][4] = {};
    __builtin_amdgcn_s_setprio(1);
#pragma unroll
    for (int ni = 0; ni < 4; ++ni) {
      const int row = ni * 16 + l16;
      const char* kr = Ks + row * 256;
      const int sw = swz(row);
      const int q16 = quad * 16;
      bf16x8 kf0 = *(const bf16x8*)(kr + ((q16 + 0)   ^ sw));
      bf16x8 kf1 = *(const bf16x8*)(kr + ((q16 + 64)  ^ sw));
      bf16x8 kf2 = *(const bf16x8*)(kr + ((q16 + 128) ^ sw));
      bf16x8 kf3 = *(const bf16x8*)(kr + ((q16 + 192) ^ sw));
      S[0][ni] = __builtin_amdgcn_mfma_f32_16x16x32_bf16(qf[0][0], kf0, S[0][ni], 0, 0, 0);
      S[1][ni] = __builtin_amdgcn_mfma_f32_16x16x32_bf16(qf[1][0], kf0, S[1][ni], 0, 0, 0);
      S[0][ni] = __builtin_amdgcn_mfma_f32_16x16x32_bf16(qf[0][1], kf1, S[0][ni], 0, 0, 0);
      S[1][ni] = __builtin_amdgcn_mfma_f32_16x16x32_bf16(qf[1][1], kf1, S[1][ni], 0, 0, 0);
      S[0][ni] = __builtin_amdgcn_mfma_f32_16x16x32_bf16(qf[0][2], kf2, S[0][ni], 0, 0, 0);
      S[1][ni] = __builtin_amdgcn_mfma_f32_16x16x32_bf16(qf[1][2], kf2, S[1][ni], 0, 0, 0);
      S[0][ni] = __builtin_amdgcn_mfma_f32_16x16x32_bf16(qf[0][3], kf3, S[0][ni], 0, 0, 0);
      S[1][ni] = __builtin_amdgcn_mfma_f32_16x16x32_bf16(qf[1][3], kf3, S[1][ni], 0, 0, 0);
    }
    __builtin_amdgcn_s_setprio(0);

    // ---- scale + causal mask + row max
    const bool diag = (t >= 2 * qt);
    const int qrow_base = qt * 128 + wave * 32;
    float rmax[2][4];
#pragma unroll
    for (int mi = 0; mi < 2; ++mi)
#pragma unroll
      for (int r = 0; r < 4; ++r) rmax[mi][r] = -1e30f;
#pragma unroll
    for (int mi = 0; mi < 2; ++mi)
#pragma unroll
      for (int ni = 0; ni < 4; ++ni) {
        int col = t * 64 + ni * 16 + l16;
#pragma unroll
        for (int r = 0; r < 4; ++r) {
          int row = qrow_base + mi * 16 + quad * 4 + r;
          float v = S[mi][ni][r] * sscale;
          if (diag && col > row) v = -1e9f;
          S[mi][ni][r] = v;
          rmax[mi][r] = fmaxf(rmax[mi][r], v);
        }
      }
    float alpha[2][4], rsum[2][4];
#pragma unroll
    for (int mi = 0; mi < 2; ++mi)
#pragma unroll
      for (int r = 0; r < 4; ++r) {
        float v = rmax[mi][r];
        v = fmaxf(v, __shfl_xor(v, 1, 64));
        v = fmaxf(v, __shfl_xor(v, 2, 64));
        v = fmaxf(v, __shfl_xor(v, 4, 64));
        v = fmaxf(v, __shfl_xor(v, 8, 64));
        float mnew = fmaxf(mrow[mi][r], v);
        alpha[mi][r] = __expf(mrow[mi][r] - mnew);
        mrow[mi][r] = mnew;
        rsum[mi][r] = 0.f;
      }

    // ---- P = exp(S - m) -> wave-local swizzled LDS rows, accumulate sums
#pragma unroll
    for (int mi = 0; mi < 2; ++mi)
#pragma unroll
      for (int ni = 0; ni < 4; ++ni)
#pragma unroll
        for (int r = 0; r < 4; ++r) {
          float p = __expf(S[mi][ni][r] - mrow[mi][r]);
          rsum[mi][r] += p;
          int prow = wave * 32 + mi * 16 + quad * 4 + r;
          int pcol2 = (ni * 16 + l16) * 2;
          *(unsigned short*)(PsB + prow * 128 + (pcol2 ^ swz(prow))) = f2b(p);
        }
#pragma unroll
    for (int mi = 0; mi < 2; ++mi)
#pragma unroll
      for (int r = 0; r < 4; ++r) {
        float v = rsum[mi][r];
        v += __shfl_xor(v, 1, 64);
        v += __shfl_xor(v, 2, 64);
        v += __shfl_xor(v, 4, 64);
        v += __shfl_xor(v, 8, 64);
        lrow[mi][r] = lrow[mi][r] * alpha[mi][r] + v;
      }
#pragma unroll
    for (int mi = 0; mi < 2; ++mi)
#pragma unroll
      for (int ni = 0; ni < 8; ++ni)
#pragma unroll
        for (int r = 0; r < 4; ++r) O[mi][ni][r] *= alpha[mi][r];

    // ---- O += P V : P A-frags from wave-local LDS, Vt B-frags from LDS tile
    bf16x8 pf[2][2];
#pragma unroll
    for (int mi = 0; mi < 2; ++mi)
#pragma unroll
      for (int ks2 = 0; ks2 < 2; ++ks2) {
        int prow = wave * 32 + mi * 16 + l16;
        pf[mi][ks2] = *(const bf16x8*)(PsB + prow * 128 +
                                       ((ks2 * 64 + quad * 16) ^ swz(prow)));
      }
    __builtin_amdgcn_s_setprio(1);
#pragma unroll
    for (int ni = 0; ni < 8; ++ni) {
      const int row = ni * 16 + l16;
      const char* vr = Vs + row * 128;
      const int sw = swz(row);
      const int q16 = quad * 16;
      bf16x8 vf0 = *(const bf16x8*)(vr + ((q16 + 0)  ^ sw));
      bf16x8 vf1 = *(const bf16x8*)(vr + ((q16 + 64) ^ sw));
      O[0][ni] = __builtin_amdgcn_mfma_f32_16x16x32_bf16(pf[0][0], vf0, O[0][ni], 0, 0, 0);
      O[1][ni] = __builtin_amdgcn_mfma_f32_16x16x32_bf16(pf[1][0], vf0, O[1][ni], 0, 0, 0);
      O[0][ni] = __builtin_amdgcn_mfma_f32_16x16x32_bf16(pf[0][1], vf1, O[0][ni], 0, 0, 0);
      O[1][ni] = __builtin_amdgcn_mfma_f32_16x16x32_bf16(pf[1][1], vf1, O[1][ni], 0, 0, 0);
    }
    __builtin_amdgcn_s_setprio(0);
  }

  // normalize + store bf16 at [s][h*128+d]
#pragma unroll
  for (int mi = 0; mi < 2; ++mi)
#pragma unroll
    for (int r = 0; r < 4; ++r) {
      float inv = 1.0f / lrow[mi][r];
      long srow = qt * 128 + wave * 32 + mi * 16 + quad * 4 + r;
#pragma unroll
      for (int ni = 0; ni < 8; ++ni) {
        long col = (long)h * HD + ni * 16 + l16;
        Ob[srow * (long)HID + col] = f2b(O[mi][ni][r] * inv);
      }
    }
}

// ---------------------------------------------------------------------------
extern "C" void kernel_launch(void* const* d_in, const int* in_sizes, int n_in,
                              void* d_out, int out_size, void* d_ws, size_t ws_size,
                              hipStream_t stream) {
  const float* hidden = (const float*)d_in[0];
  const float* wq = (const float*)d_in[1];
  const float* wk = (const float*)d_in[2];
  const float* wv = (const float*)d_in[3];
  const float* wo = (const float*)d_in[4];
  const int* pos = (const int*)d_in[5];
  float* out = (float*)d_out;

  // workspace layout (bytes); total 138,412,032. Overlays: Qb=hid_b (hid dead
  // after GEMM1), attn_b=qkv_b (qkv dead after postproc).
  char* ws = (char*)d_ws;
  unsigned short* wqkv_b = (unsigned short*)(ws);               // 50,331,648
  unsigned short* wo_b   = (unsigned short*)(ws + 50331648);    // 33,554,432
  unsigned short* hid_b  = (unsigned short*)(ws + 83886080);    // 16,777,216
  unsigned short* qkv_b  = (unsigned short*)(ws + 100663296);   // 25,165,824
  unsigned short* Kb     = (unsigned short*)(ws + 125829120);   //  4,194,304
  unsigned short* Vb     = (unsigned short*)(ws + 130023424);   //  4,194,304
  unsigned short* Vtb    = (unsigned short*)(ws + 134217728);   //  4,194,304
  unsigned short* Qb     = hid_b;
  unsigned short* attn_b = qkv_b;

  cast_kernel<<<8388608 / 1024, 256, 0, stream>>>(hidden, hid_b, 8388608 / 4);
  cast_kernel<<<16777216 / 1024, 256, 0, stream>>>(wq, wqkv_b, 16777216 / 4);
  cast_kernel<<<4194304 / 1024, 256, 0, stream>>>(wk, wqkv_b + 16777216, 4194304 / 4);
  cast_kernel<<<4194304 / 1024, 256, 0, stream>>>(wv, wqkv_b + 20971520, 4194304 / 4);
  cast_kernel<<<16777216 / 1024, 256, 0, stream>>>(wo, wo_b, 16777216 / 4);

  gemm_bt<1><<<dim3(QKV_N / 256, S_LEN / 256), 512, 0, stream>>>(
      hid_b, wqkv_b, (void*)qkv_b, S_LEN, QKV_N, HID);

  postproc<<<S_LEN, 256, 0, stream>>>(qkv_b, pos, Qb, Kb, Vb);
  transpose_v<<<NKV * 32, 256, 0, stream>>>(Vb, Vtb);
  attn_kernel<<<NH * 16, 256, 0, stream>>>(Qb, Kb, Vtb, attn_b);

  gemm_bt<0><<<dim3(HID / 256, S_LEN / 256), 512, 0, stream>>>(
      attn_b, wo_b, (void*)out, S_LEN, HID, HID);
}

// Round 4
// 551.108 us; speedup vs baseline: 1.0669x; 1.0007x over previous
//
#include <hip/hip_runtime.h>

// ---------------------------------------------------------------------------
// LlamaAttention_Tender: hidden(2048x4096) -> QKV proj -> RoPE -> int8 qdq(K,V)
// -> GQA causal attention (32 q-heads, 8 kv-heads, D=128) -> out proj.
// R6: GEMM K-loop fused: 2 barriers/tile (was 8), all 64 MFMAs of a tile run
//     back-to-back with counted lgkmcnt waits; h1-fragment reads issued early
//     so they complete under MFMA shadow. Hazards: barrier#1 protects h1
//     stages vs prev tile's h1 reads; barrier#2 (after lgkm(4)=h0 reads done)
//     protects h0 stages. vmcnt(4) tile fence unchanged. A-h1 re-reads reuse
//     A-h0's registers (peak 64 frag VGPRs, no occupancy cliff).
//     Out-proj: split-K=2 (grid 16x8x2 = 256 blocks, was 128 = half chip
//     idle) with f32 atomicAdd epilogue onto memset-zeroed out.
// ---------------------------------------------------------------------------

#define S_LEN 2048
#define HID 4096
#define NH 32
#define NKV 8
#define HD 128
#define QKV_N 6144   // 4096 q + 1024 k + 1024 v

typedef __bf16 bf16x8 __attribute__((ext_vector_type(8)));
typedef float f32x4 __attribute__((ext_vector_type(4)));

__device__ __forceinline__ unsigned short f2b(float f) {
  unsigned int u = __float_as_uint(f);
  u += 0x7fffu + ((u >> 16) & 1u);   // round-to-nearest-even
  return (unsigned short)(u >> 16);
}
__device__ __forceinline__ float b2f(unsigned short h) {
  return __uint_as_float(((unsigned int)h) << 16);
}
// async global->LDS, 16B per lane. LDS dst must be wave-uniform (lane*16 implicit).
__device__ __forceinline__ void gl_lds16(const void* g, void* l) {
  __builtin_amdgcn_global_load_lds(
      (__attribute__((address_space(1))) void*)g,
      (__attribute__((address_space(3))) void*)l, 16, 0, 0);
}
// compiler-opaque LDS b128 read: no alias info, so no auto-inserted vmcnt
// waits against in-flight global_load_lds prefetches. Ordering enforced
// manually via s_waitcnt lgkmcnt + sched_barrier at the use point.
__device__ __forceinline__ bf16x8 ds_read128(const void* p) {
  bf16x8 r;
  unsigned a = (unsigned)(unsigned long long)
      (__attribute__((address_space(3))) const void*)p;
  asm volatile("ds_read_b128 %0, %1" : "=v"(r) : "v"(a));
  return r;
}
// LDS bank-spread swizzle: permutes 16B chunks within a 128B row; involution.
__device__ __forceinline__ int swz(int row) {
  return ((row & 7) << 4) ^ (((row >> 3) & 1) << 5);
}
// barrier without the __syncthreads vmcnt(0) drain; asm fences stop IR motion
__device__ __forceinline__ void barrier_np() {
  asm volatile("" ::: "memory");
  __builtin_amdgcn_s_barrier();
  asm volatile("" ::: "memory");
}

// ---------------------------------------------------------------- cast fp32->bf16
__global__ __launch_bounds__(256) void cast_kernel(const float* __restrict__ src,
                                                   unsigned short* __restrict__ dst,
                                                   int n4) {
  int i = blockIdx.x * 256 + threadIdx.x;
  if (i >= n4) return;
  float4 v = ((const float4*)src)[i];
  ushort4 o;
  o.x = f2b(v.x); o.y = f2b(v.y); o.z = f2b(v.z); o.w = f2b(v.w);
  ((ushort4*)dst)[i] = o;
}

// --------------------------------------------- B^T GEMM, 256x256 fused-tile loop
// C[M,N] = A[M,K]*B[N,K]^T. 512 thr = 8 waves (2Mx4N), per-wave out 128x64.
// LDS 128KB: [buf][A 32K | B 32K], halves of 16KB. BK=64, NT=Klen/64 tiles.
// CMODE: 0 = f32 store, 1 = bf16 store, 2 = f32 atomicAdd (split-K).
template <int CMODE, int SPLITK>
__global__ __launch_bounds__(512, 2) void gemm_bt(const unsigned short* __restrict__ A,
                                                  const unsigned short* __restrict__ B,
                                                  void* __restrict__ Cout,
                                                  int M, int N, int K) {
  __shared__ __align__(16) char lds[131072];
  const int tid = threadIdx.x;
  const int lane = tid & 63, wave = tid >> 6;
  const int quad = lane >> 4, l16 = lane & 15;
  const int wave_m = wave >> 2, wave_n = wave & 3;
  const long row0 = (long)blockIdx.y * 256;
  const long col0 = (long)blockIdx.x * 256;
  const int Klen = K / SPLITK;
  const int NT = Klen >> 6;
  const long rowstride = (long)K * 2;
  const unsigned short* Ag = A + (long)blockIdx.z * Klen;
  const unsigned short* Bg = B + (long)blockIdx.z * Klen;

  f32x4 acc[8][4] = {};

  // stage one 16KB half-tile: operand base offset ob (0=A,32768=B), tile T,
  // half h, target buffer tbuf. 2 gl_lds per wave.
  auto stage = [&](const unsigned short* G, long base0, int ob, int T, int h, int tbuf) {
    if (T >= NT) return;
    char* dst = lds + tbuf * 65536 + ob + h * 16384 + wave * 1024;
    const char* src = (const char*)G + (base0 + h * 128) * rowstride + (long)T * 128;
#pragma unroll
    for (int c = 0; c < 2; ++c) {
      int b = c * 8192 + wave * 1024 + lane * 16;
      int r = b >> 7, cb = b & 127;
      gl_lds16(src + (long)r * rowstride + (cb ^ swz(r)), dst + c * 8192);
    }
  };

#define STAGE_A(T, h, tbuf) stage(Ag, row0, 0, (T), (h), (tbuf))
#define STAGE_B(T, h, tbuf) stage(Bg, col0, 32768, (T), (h), (tbuf))

  // A-half (8 reads) / B-half (4 reads) register loads, swizzled addresses
  auto readA = [&](const char* base, bf16x8 (&a)[2][4]) {
#pragma unroll
    for (int mi = 0; mi < 4; ++mi) {
      int r = wave_m * 64 + mi * 16 + l16;
      const char* rp = base + r * 128;
      int sw = swz(r);
      a[0][mi] = ds_read128(rp + ((quad * 16) ^ sw));
      a[1][mi] = ds_read128(rp + ((64 + quad * 16) ^ sw));
    }
  };
  auto readB = [&](const char* base, bf16x8 (&b)[2][2]) {
#pragma unroll
    for (int ni = 0; ni < 2; ++ni) {
      int r = wave_n * 32 + ni * 16 + l16;
      const char* rp = base + r * 128;
      int sw = swz(r);
      b[0][ni] = ds_read128(rp + ((quad * 16) ^ sw));
      b[1][ni] = ds_read128(rp + ((64 + quad * 16) ^ sw));
    }
  };

#define WAITL(n)                                               \
  do {                                                         \
    asm volatile("s_waitcnt lgkmcnt(" #n ")" ::: "memory");    \
    __builtin_amdgcn_sched_barrier(0);                         \
  } while (0)

#define MFMA_BLOCK(MH, NHh, A_, B_)                                          \
  do {                                                                       \
    __builtin_amdgcn_s_setprio(1);                                           \
    _Pragma("unroll")                                                        \
    for (int ks = 0; ks < 2; ++ks)                                           \
      _Pragma("unroll")                                                      \
      for (int mi = 0; mi < 4; ++mi)                                         \
        _Pragma("unroll")                                                    \
        for (int ni = 0; ni < 2; ++ni)                                       \
          acc[(MH) * 4 + mi][(NHh) * 2 + ni] =                               \
              __builtin_amdgcn_mfma_f32_16x16x32_bf16(                       \
                  A_[ks][mi], B_[ks][ni],                                    \
                  acc[(MH) * 4 + mi][(NHh) * 2 + ni], 0, 0, 0);              \
    __builtin_amdgcn_s_setprio(0);                                           \
  } while (0)

  // prologue: T0 fully + T1 h0; vmcnt(4) leaves only T1-h0's 4 loads open
  STAGE_A(0, 0, 0); STAGE_B(0, 0, 0); STAGE_A(0, 1, 0); STAGE_B(0, 1, 0);
  STAGE_A(1, 0, 1); STAGE_B(1, 0, 1);
  asm volatile("s_waitcnt vmcnt(4)" ::: "memory");

  for (int g = 0; g < NT; ++g) {
    const int buf = g & 1;
    const char* Ab = lds + buf * 65536;
    const char* Bb = Ab + 32768;
    bf16x8 a[2][4], b0[2][2], b1[2][2];

    barrier_np();                       // #1: prev tile's h1 reads all done
    readA(Ab, a);                       // A h0 (8 reads)
    readB(Bb, b0);                      // B h0 (4)
    readB(Bb + 16384, b1);              // B h1 (4)
    STAGE_A(g + 1, 1, buf ^ 1);         // h1 of next tile -> other buffer
    STAGE_B(g + 1, 1, buf ^ 1);
    WAITL(4);                           // a,b0 (oldest 12 of 16) complete
    barrier_np();                       // #2: all waves' h0 reads done
    STAGE_A(g + 2, 0, buf);             // h0 of tile+2 -> overwrite this buf h0
    STAGE_B(g + 2, 0, buf);
    MFMA_BLOCK(0, 0, a, b0);
    WAITL(0);                           // b1 complete
    MFMA_BLOCK(0, 1, a, b1);
    readA(Ab + 16384, a);               // A h1 (8 reads, reuse regs; a dead)
    WAITL(0);
    MFMA_BLOCK(1, 0, a, b0);
    MFMA_BLOCK(1, 1, a, b1);
    if (g + 2 < NT) { asm volatile("s_waitcnt vmcnt(4)" ::: "memory"); }
    else            { asm volatile("s_waitcnt vmcnt(0)" ::: "memory"); }
  }
#undef STAGE_A
#undef STAGE_B
#undef WAITL
#undef MFMA_BLOCK

  // epilogue: C write (C/D layout: col=l16, row=quad*4+r per 16x16 frag)
#pragma unroll
  for (int mi = 0; mi < 8; ++mi) {
    const int mh = mi >> 2, mq = mi & 3;
#pragma unroll
    for (int ni = 0; ni < 4; ++ni) {
      const int nh = ni >> 1, nq = ni & 1;
#pragma unroll
      for (int r = 0; r < 4; ++r) {
        long row = row0 + mh * 128 + wave_m * 64 + mq * 16 + quad * 4 + r;
        long col = col0 + nh * 128 + wave_n * 32 + nq * 16 + l16;
        float v = acc[mi][ni][r];
        if (CMODE == 1)      ((unsigned short*)Cout)[row * N + col] = f2b(v);
        else if (CMODE == 2) atomicAdd((float*)Cout + row * N + col, v);
        else                 ((float*)Cout)[row * N + col] = v;
      }
    }
  }
}

// ------------------------------------------- RoPE + sym int8 quant-dequant + split
// qkv[2048][6144] bf16 -> Qb[32][2048][128], Kb[8][2048][128], Vb[8][2048][128]
__global__ __launch_bounds__(256) void postproc(const unsigned short* __restrict__ qkv,
                                                const int* __restrict__ pos_ids,
                                                unsigned short* __restrict__ Qb,
                                                unsigned short* __restrict__ Kb,
                                                unsigned short* __restrict__ Vb) {
  const int s = blockIdx.x;
  const int lane = threadIdx.x & 63, wave = threadIdx.x >> 6;
  const float pos = (float)pos_ids[s];
  // inv_freq = 10000^(-lane/64) = exp(-lane * ln(10000)/64); pair (d, d+64)
  const float invf = expf(-(float)lane * 0.14391156831212787f);
  const float ang = pos * invf;
  const float ca = cosf(ang), sa = sinf(ang);

  for (int r = wave; r < 48; r += 4) {
    if (r < 32) {                 // Q head r: rope only
      const unsigned short* src = qkv + (long)s * QKV_N + r * HD;
      float x0 = b2f(src[lane]), x1 = b2f(src[lane + 64]);
      unsigned short* dst = Qb + ((long)r * S_LEN + s) * HD;
      dst[lane]      = f2b(x0 * ca - x1 * sa);
      dst[lane + 64] = f2b(x1 * ca + x0 * sa);
    } else if (r < 40) {          // K head r-32: rope then quant-dequant
      int h = r - 32;
      const unsigned short* src = qkv + (long)s * QKV_N + 4096 + h * HD;
      float x0 = b2f(src[lane]), x1 = b2f(src[lane + 64]);
      float y0 = x0 * ca - x1 * sa;
      float y1 = x1 * ca + x0 * sa;
      float m = fmaxf(fabsf(y0), fabsf(y1));
      for (int off = 32; off; off >>= 1) m = fmaxf(m, __shfl_xor(m, off, 64));
      float scale = fmaxf(m / 127.0f, 1e-9f);
      float q0 = fminf(fmaxf(rintf(y0 / scale), -128.f), 127.f);
      float q1 = fminf(fmaxf(rintf(y1 / scale), -128.f), 127.f);
      unsigned short* dst = Kb + ((long)h * S_LEN + s) * HD;
      dst[lane]      = f2b(q0 * scale);
      dst[lane + 64] = f2b(q1 * scale);
    } else {                      // V head r-40: quant-dequant only
      int h = r - 40;
      const unsigned short* src = qkv + (long)s * QKV_N + 5120 + h * HD;
      float x0 = b2f(src[lane]), x1 = b2f(src[lane + 64]);
      float m = fmaxf(fabsf(x0), fabsf(x1));
      for (int off = 32; off; off >>= 1) m = fmaxf(m, __shfl_xor(m, off, 64));
      float scale = fmaxf(m / 127.0f, 1e-9f);
      float q0 = fminf(fmaxf(rintf(x0 / scale), -128.f), 127.f);
      float q1 = fminf(fmaxf(rintf(x1 / scale), -128.f), 127.f);
      unsigned short* dst = Vb + ((long)h * S_LEN + s) * HD;
      dst[lane]      = f2b(q0 * scale);
      dst[lane + 64] = f2b(q1 * scale);
    }
  }
}

// -------------------------------------------------- V transpose: [h][s][d]->[h][d][s]
__global__ __launch_bounds__(256) void transpose_v(const unsigned short* __restrict__ Vb,
                                                   unsigned short* __restrict__ Vtb) {
  __shared__ unsigned short t[64][136];
  const int h = blockIdx.x >> 5, st = blockIdx.x & 31;
  const int tid = threadIdx.x;
  const long vbase = (long)h * S_LEN * HD;
#pragma unroll
  for (int p = 0; p < 8; ++p) {
    int e = p * 1024 + tid * 4;
    int sl = e >> 7, d = e & 127;
    ushort4 v = *(const ushort4*)(Vb + vbase + (long)(st * 64 + sl) * HD + d);
    t[sl][d] = v.x; t[sl][d + 1] = v.y; t[sl][d + 2] = v.z; t[sl][d + 3] = v.w;
  }
  __syncthreads();
  const long tbase = (long)h * HD * S_LEN;
#pragma unroll
  for (int p = 0; p < 8; ++p) {
    int o = p * 1024 + tid * 4;
    int d = o >> 6, sl = o & 63;
    ushort4 v;
    v.x = t[sl][d]; v.y = t[sl + 1][d]; v.z = t[sl + 2][d]; v.w = t[sl + 3][d];
    *(ushort4*)(Vtb + tbase + (long)d * S_LEN + st * 64 + sl) = v;
  }
}

// ------------------------------------------------------------- flash attention
// Block = (head, 128-row q-tile), 4 waves x 32 q-rows. KVBLK=64.
// K tile [64 keys][128 d] and Vt tile [128 d][64 keys] staged in LDS via
// global_load_lds (shared by all waves), double-buffered 2-phase:
//   barrier(drains prev stage) -> issue stage(t+1) -> compute(t).
// XOR swizzle on K/Vt/Ps rows applied on BOTH the pre-swizzled global source
// (linear LDS dest, rule #21) and the ds_read/ds_write side -> conflict-free.
// LDS: K 2x16K + Vt 2x16K + Ps 16K = 80 KB exactly -> 2 blocks/CU.
// Complementary qt pairing: steps/pair = (2qt+2)+(2(15-qt)+2) = 34, balanced.
__global__ __launch_bounds__(256, 2) void attn_kernel(const unsigned short* __restrict__ Qb,
                                                      const unsigned short* __restrict__ Kb,
                                                      const unsigned short* __restrict__ Vtb,
                                                      unsigned short* __restrict__ Ob) {
  __shared__ __align__(16) char lds[81920];
  // layout: K buf0 @0, K buf1 @16384, V buf0 @32768, V buf1 @49152, Ps @65536

  const int bx = blockIdx.x;
  const int p8 = bx & 1;
  const int g = (bx >> 1) & 7;
  const int b8 = bx >> 8;
  const int qt = (p8 ^ b8) ? (15 - g) : g;
  const int h = ((bx >> 4) & 15) + 16 * b8;
  const int hk = h >> 2;                        // GQA: 4 q-heads per kv-head
  const int tid = threadIdx.x;
  const int lane = tid & 63, wave = tid >> 6;
  const int quad = lane >> 4, l16 = lane & 15;

  // Q fragments for this wave's 32 rows (A-operand layout), from global
  bf16x8 qf[2][4];
  {
    const unsigned short* qb =
        Qb + ((long)h * S_LEN + qt * 128 + wave * 32 + l16) * HD + quad * 8;
#pragma unroll
    for (int mi = 0; mi < 2; ++mi)
#pragma unroll
      for (int ks = 0; ks < 4; ++ks)
        qf[mi][ks] = *(const bf16x8*)(qb + mi * 16 * HD + ks * 32);
  }

  f32x4 O[2][8] = {};
  float mrow[2][4], lrow[2][4];
#pragma unroll
  for (int mi = 0; mi < 2; ++mi)
#pragma unroll
    for (int r = 0; r < 4; ++r) { mrow[mi][r] = -1e30f; lrow[mi][r] = 0.f; }

  const char* Kg = (const char*)(Kb + (long)hk * S_LEN * HD);
  const char* Vg = (const char*)(Vtb + (long)hk * HD * S_LEN);
  char* PsB = lds + 65536;
  const float sscale = 0.08838834764831845f;  // 1/sqrt(128)
  const int nsteps = 2 * qt + 2;              // 64-key steps

  // stage one 64-key K tile (16 KB, contiguous rows in global) into buf
  auto stageK = [&](int step, int buf) {
    char* dst = lds + buf * 16384 + wave * 1024;
    const char* src = Kg + (long)step * 16384;
#pragma unroll
    for (int c = 0; c < 4; ++c) {
      int f = c * 4096 + tid * 16;
      int row = f >> 8, wb = f & 255;
      gl_lds16(src + row * 256 + (wb ^ swz(row)), dst + c * 4096);
    }
  };
  // stage one Vt tile [128 d][64 keys] (d-rows strided 4096B in global)
  auto stageV = [&](int step, int buf) {
    char* dst = lds + 32768 + buf * 16384 + wave * 1024;
    const char* src = Vg + (long)step * 128;
#pragma unroll
    for (int c = 0; c < 4; ++c) {
      int f = c * 4096 + tid * 16;
      int d = f >> 7, wb = f & 127;
      gl_lds16(src + (long)d * (S_LEN * 2) + (wb ^ swz(d)), dst + c * 4096);
    }
  };

  stageK(0, 0);
  stageV(0, 0);

  for (int t = 0; t < nsteps; ++t) {
    __syncthreads();   // drains this wave's stage (vmcnt 0) + syncs all waves
    if (t + 1 < nsteps) {
      stageK(t + 1, (t + 1) & 1);
      stageV(t + 1, (t + 1) & 1);
    }
    const char* Ks = lds + (t & 1) * 16384;
    const char* Vs = lds + 32768 + (t & 1) * 16384;

    // ---- S = Q K^T over 64 keys (4 ni of 16)
    f32x4 S[2][4] = {};
    __builtin_amdgcn_s_setprio(1);
#pragma unroll
    for (int ni = 0; ni < 4; ++ni) {
      const int row = ni * 16 + l16;
      const char* kr = Ks + row * 256;
      const int sw = swz(row);
      const int q16 = quad * 16;
      bf16x8 kf0 = *(const bf16x8*)(kr + ((q16 + 0)   ^ sw));
      bf16x8 kf1 = *(const bf16x8*)(kr + ((q16 + 64)  ^ sw));
      bf16x8 kf2 = *(const bf16x8*)(kr + ((q16 + 128) ^ sw));
      bf16x8 kf3 = *(const bf16x8*)(kr + ((q16 + 192) ^ sw));
      S[0][ni] = __builtin_amdgcn_mfma_f32_16x16x32_bf16(qf[0][0], kf0, S[0][ni], 0, 0, 0);
      S[1][ni] = __builtin_amdgcn_mfma_f32_16x16x32_bf16(qf[1][0], kf0, S[1][ni], 0, 0, 0);
      S[0][ni] = __builtin_amdgcn_mfma_f32_16x16x32_bf16(qf[0][1], kf1, S[0][ni], 0, 0, 0);
      S[1][ni] = __builtin_amdgcn_mfma_f32_16x16x32_bf16(qf[1][1], kf1, S[1][ni], 0, 0, 0);
      S[0][ni] = __builtin_amdgcn_mfma_f32_16x16x32_bf16(qf[0][2], kf2, S[0][ni], 0, 0, 0);
      S[1][ni] = __builtin_amdgcn_mfma_f32_16x16x32_bf16(qf[1][2], kf2, S[1][ni], 0, 0, 0);
      S[0][ni] = __builtin_amdgcn_mfma_f32_16x16x32_bf16(qf[0][3], kf3, S[0][ni], 0, 0, 0);
      S[1][ni] = __builtin_amdgcn_mfma_f32_16x16x32_bf16(qf[1][3], kf3, S[1][ni], 0, 0, 0);
    }
    __builtin_amdgcn_s_setprio(0);

    // ---- scale + causal mask + row max
    const bool diag = (t >= 2 * qt);
    const int qrow_base = qt * 128 + wave * 32;
    float rmax[2][4];
#pragma unroll
    for (int mi = 0; mi < 2; ++mi)
#pragma unroll
      for (int r = 0; r < 4; ++r) rmax[mi][r] = -1e30f;
#pragma unroll
    for (int mi = 0; mi < 2; ++mi)
#pragma unroll
      for (int ni = 0; ni < 4; ++ni) {
        int col = t * 64 + ni * 16 + l16;
#pragma unroll
        for (int r = 0; r < 4; ++r) {
          int row = qrow_base + mi * 16 + quad * 4 + r;
          float v = S[mi][ni][r] * sscale;
          if (diag && col > row) v = -1e9f;
          S[mi][ni][r] = v;
          rmax[mi][r] = fmaxf(rmax[mi][r], v);
        }
      }
    float alpha[2][4], rsum[2][4];
#pragma unroll
    for (int mi = 0; mi < 2; ++mi)
#pragma unroll
      for (int r = 0; r < 4; ++r) {
        float v = rmax[mi][r];
        v = fmaxf(v, __shfl_xor(v, 1, 64));
        v = fmaxf(v, __shfl_xor(v, 2, 64));
        v = fmaxf(v, __shfl_xor(v, 4, 64));
        v = fmaxf(v, __shfl_xor(v, 8, 64));
        float mnew = fmaxf(mrow[mi][r], v);
        alpha[mi][r] = __expf(mrow[mi][r] - mnew);
        mrow[mi][r] = mnew;
        rsum[mi][r] = 0.f;
      }

    // ---- P = exp(S - m) -> wave-local swizzled LDS rows, accumulate sums
#pragma unroll
    for (int mi = 0; mi < 2; ++mi)
#pragma unroll
      for (int ni = 0; ni < 4; ++ni)
#pragma unroll
        for (int r = 0; r < 4; ++r) {
          float p = __expf(S[mi][ni][r] - mrow[mi][r]);
          rsum[mi][r] += p;
          int prow = wave * 32 + mi * 16 + quad * 4 + r;
          int pcol2 = (ni * 16 + l16) * 2;
          *(unsigned short*)(PsB + prow * 128 + (pcol2 ^ swz(prow))) = f2b(p);
        }
#pragma unroll
    for (int mi = 0; mi < 2; ++mi)
#pragma unroll
      for (int r = 0; r < 4; ++r) {
        float v = rsum[mi][r];
        v += __shfl_xor(v, 1, 64);
        v += __shfl_xor(v, 2, 64);
        v += __shfl_xor(v, 4, 64);
        v += __shfl_xor(v, 8, 64);
        lrow[mi][r] = lrow[mi][r] * alpha[mi][r] + v;
      }
#pragma unroll
    for (int mi = 0; mi < 2; ++mi)
#pragma unroll
      for (int ni = 0; ni < 8; ++ni)
#pragma unroll
        for (int r = 0; r < 4; ++r) O[mi][ni][r] *= alpha[mi][r];

    // ---- O += P V : P A-frags from wave-local LDS, Vt B-frags from LDS tile
    bf16x8 pf[2][2];
#pragma unroll
    for (int mi = 0; mi < 2; ++mi)
#pragma unroll
      for (int ks2 = 0; ks2 < 2; ++ks2) {
        int prow = wave * 32 + mi * 16 + l16;
        pf[mi][ks2] = *(const bf16x8*)(PsB + prow * 128 +
                                       ((ks2 * 64 + quad * 16) ^ swz(prow)));
      }
    __builtin_amdgcn_s_setprio(1);
#pragma unroll
    for (int ni = 0; ni < 8; ++ni) {
      const int row = ni * 16 + l16;
      const char* vr = Vs + row * 128;
      const int sw = swz(row);
      const int q16 = quad * 16;
      bf16x8 vf0 = *(const bf16x8*)(vr + ((q16 + 0)  ^ sw));
      bf16x8 vf1 = *(const bf16x8*)(vr + ((q16 + 64) ^ sw));
      O[0][ni] = __builtin_amdgcn_mfma_f32_16x16x32_bf16(pf[0][0], vf0, O[0][ni], 0, 0, 0);
      O[1][ni] = __builtin_amdgcn_mfma_f32_16x16x32_bf16(pf[1][0], vf0, O[1][ni], 0, 0, 0);
      O[0][ni] = __builtin_amdgcn_mfma_f32_16x16x32_bf16(pf[0][1], vf1, O[0][ni], 0, 0, 0);
      O[1][ni] = __builtin_amdgcn_mfma_f32_16x16x32_bf16(pf[1][1], vf1, O[1][ni], 0, 0, 0);
    }
    __builtin_amdgcn_s_setprio(0);
  }

  // normalize + store bf16 at [s][h*128+d]
#pragma unroll
  for (int mi = 0; mi < 2; ++mi)
#pragma unroll
    for (int r = 0; r < 4; ++r) {
      float inv = 1.0f / lrow[mi][r];
      long srow = qt * 128 + wave * 32 + mi * 16 + quad * 4 + r;
#pragma unroll
      for (int ni = 0; ni < 8; ++ni) {
        long col = (long)h * HD + ni * 16 + l16;
        Ob[srow * (long)HID + col] = f2b(O[mi][ni][r] * inv);
      }
    }
}

// ---------------------------------------------------------------------------
extern "C" void kernel_launch(void* const* d_in, const int* in_sizes, int n_in,
                              void* d_out, int out_size, void* d_ws, size_t ws_size,
                              hipStream_t stream) {
  const float* hidden = (const float*)d_in[0];
  const float* wq = (const float*)d_in[1];
  const float* wk = (const float*)d_in[2];
  const float* wv = (const float*)d_in[3];
  const float* wo = (const float*)d_in[4];
  const int* pos = (const int*)d_in[5];
  float* out = (float*)d_out;

  // workspace layout (bytes); total 138,412,032. Overlays: Qb=hid_b (hid dead
  // after GEMM1), attn_b=qkv_b (qkv dead after postproc).
  char* ws = (char*)d_ws;
  unsigned short* wqkv_b = (unsigned short*)(ws);               // 50,331,648
  unsigned short* wo_b   = (unsigned short*)(ws + 50331648);    // 33,554,432
  unsigned short* hid_b  = (unsigned short*)(ws + 83886080);    // 16,777,216
  unsigned short* qkv_b  = (unsigned short*)(ws + 100663296);   // 25,165,824
  unsigned short* Kb     = (unsigned short*)(ws + 125829120);   //  4,194,304
  unsigned short* Vb     = (unsigned short*)(ws + 130023424);   //  4,194,304
  unsigned short* Vtb    = (unsigned short*)(ws + 134217728);   //  4,194,304
  unsigned short* Qb     = hid_b;
  unsigned short* attn_b = qkv_b;

  cast_kernel<<<8388608 / 1024, 256, 0, stream>>>(hidden, hid_b, 8388608 / 4);
  cast_kernel<<<16777216 / 1024, 256, 0, stream>>>(wq, wqkv_b, 16777216 / 4);
  cast_kernel<<<4194304 / 1024, 256, 0, stream>>>(wk, wqkv_b + 16777216, 4194304 / 4);
  cast_kernel<<<4194304 / 1024, 256, 0, stream>>>(wv, wqkv_b + 20971520, 4194304 / 4);
  cast_kernel<<<16777216 / 1024, 256, 0, stream>>>(wo, wo_b, 16777216 / 4);

  gemm_bt<1, 1><<<dim3(QKV_N / 256, S_LEN / 256), 512, 0, stream>>>(
      hid_b, wqkv_b, (void*)qkv_b, S_LEN, QKV_N, HID);

  postproc<<<S_LEN, 256, 0, stream>>>(qkv_b, pos, Qb, Kb, Vb);
  transpose_v<<<NKV * 32, 256, 0, stream>>>(Vb, Vtb);
  attn_kernel<<<NH * 16, 256, 0, stream>>>(Qb, Kb, Vtb, attn_b);

  // out-proj: split-K=2 -> 256 blocks (full chip); atomicAdd onto zeroed out
  hipMemsetAsync(out, 0, (size_t)S_LEN * HID * 4, stream);
  gemm_bt<2, 2><<<dim3(HID / 256, S_LEN / 256, 2), 512, 0, stream>>>(
      attn_b, wo_b, (void*)out, S_LEN, HID, HID);
}

// Round 5
// 489.580 us; speedup vs baseline: 1.2010x; 1.1257x over previous
//
#include <hip/hip_runtime.h>

// ---------------------------------------------------------------------------
// LlamaAttention_Tender: hidden(2048x4096) -> QKV proj -> RoPE -> int8 qdq(K,V)
// -> GQA causal attention (32 q-heads, 8 kv-heads, D=128) -> out proj.
// R7: GEMMs re-tiled for TLP + full fill (R4-R6 showed schedule-insensitivity
//     at 1 block/CU): 256-thr 4-wave blocks, 2 blocks/CU, 100% grid fill.
//     QKV 128x192 (grid 32x16=512, LDS 80KB x2 = full 160KB pool);
//     out-proj 128x128 (grid 32x16=512, LDS 64KB). Fused 2-barrier loop,
//     opaque ds_reads, both-sides swizzle, counted vmcnt(HOPS=2+BN/64).
//     Fence invariant: carry = h0(g+1); vmcnt(HOPS) completes h0+h1 of g+1.
// ---------------------------------------------------------------------------

#define S_LEN 2048
#define HID 4096
#define NH 32
#define NKV 8
#define HD 128
#define QKV_N 6144   // 4096 q + 1024 k + 1024 v

typedef __bf16 bf16x8 __attribute__((ext_vector_type(8)));
typedef float f32x4 __attribute__((ext_vector_type(4)));

__device__ __forceinline__ unsigned short f2b(float f) {
  unsigned int u = __float_as_uint(f);
  u += 0x7fffu + ((u >> 16) & 1u);   // round-to-nearest-even
  return (unsigned short)(u >> 16);
}
__device__ __forceinline__ float b2f(unsigned short h) {
  return __uint_as_float(((unsigned int)h) << 16);
}
// async global->LDS, 16B per lane. LDS dst must be wave-uniform (lane*16 implicit).
__device__ __forceinline__ void gl_lds16(const void* g, void* l) {
  __builtin_amdgcn_global_load_lds(
      (__attribute__((address_space(1))) void*)g,
      (__attribute__((address_space(3))) void*)l, 16, 0, 0);
}
// compiler-opaque LDS b128 read (no alias info -> no auto vmcnt drains).
__device__ __forceinline__ bf16x8 ds_read128(const void* p) {
  bf16x8 r;
  unsigned a = (unsigned)(unsigned long long)
      (__attribute__((address_space(3))) const void*)p;
  asm volatile("ds_read_b128 %0, %1" : "=v"(r) : "v"(a));
  return r;
}
// LDS bank-spread swizzle: permutes 16B chunks within a 128B row; involution.
__device__ __forceinline__ int swz(int row) {
  return ((row & 7) << 4) ^ (((row >> 3) & 1) << 5);
}
// barrier without the __syncthreads vmcnt(0) drain; asm fences stop IR motion
__device__ __forceinline__ void barrier_np() {
  asm volatile("" ::: "memory");
  __builtin_amdgcn_s_barrier();
  asm volatile("" ::: "memory");
}
#define WAITL0                                            \
  do {                                                    \
    asm volatile("s_waitcnt lgkmcnt(0)" ::: "memory");    \
    __builtin_amdgcn_sched_barrier(0);                    \
  } while (0)

// ---------------------------------------------------------------- cast fp32->bf16
__global__ __launch_bounds__(256) void cast_kernel(const float* __restrict__ src,
                                                   unsigned short* __restrict__ dst,
                                                   int n4) {
  int i = blockIdx.x * 256 + threadIdx.x;
  if (i >= n4) return;
  float4 v = ((const float4*)src)[i];
  ushort4 o;
  o.x = f2b(v.x); o.y = f2b(v.y); o.z = f2b(v.z); o.w = f2b(v.w);
  ((ushort4*)dst)[i] = o;
}

// --------------------------------- B^T GEMM, 128xBN tile, 4 waves, 2 blocks/CU
// C[M,N] = A[M,K]*B[N,K]^T. 256 thr = 4 waves (2Mx2N), per-wave out 64x(BN/2).
// LDS per buffer: A 16KB + B BN*128B; double-buffered. BK=64, NT=K/64.
// CMODE: 0 = f32 store, 1 = bf16 store.
template <int BN, int CMODE>
__global__ __launch_bounds__(256, 2) void gemm_bt(const unsigned short* __restrict__ A,
                                                  const unsigned short* __restrict__ B,
                                                  void* __restrict__ Cout,
                                                  int M, int N, int K) {
  constexpr int NI = BN / 32;                 // per-wave ni count (6 or 4)
  constexpr int BSTRIDE = 16384 + BN * 128;   // per-buffer LDS bytes
  __shared__ __align__(16) char lds[2 * BSTRIDE];
  const int tid = threadIdx.x;
  const int lane = tid & 63, wave = tid >> 6;
  const int quad = lane >> 4, l16 = lane & 15;
  const int wave_m = wave >> 1, wave_n = wave & 1;
  const long row0 = (long)blockIdx.y * 128;
  const long col0 = (long)blockIdx.x * BN;
  const int NT = K >> 6;
  const long rowstride = (long)K * 2;

  f32x4 acc[4][NI] = {};

  // stage A half-tile (64 rows, 8KB): 2 gl_lds per wave
  auto stageA = [&](int T, int h, int buf) {
    if (T >= NT) return;
    char* dst = lds + buf * BSTRIDE + h * 8192 + wave * 1024;
    const char* src = (const char*)A + (row0 + h * 64) * rowstride + (long)T * 128;
#pragma unroll
    for (int c = 0; c < 2; ++c) {
      int b = c * 4096 + wave * 1024 + lane * 16;
      int r = b >> 7, cb = b & 127;
      gl_lds16(src + (long)r * rowstride + (cb ^ swz(r)), dst + c * 4096);
    }
  };
  // stage B half-tile (BN/2 rows): BN/64 gl_lds per wave
  auto stageB = [&](int T, int h, int buf) {
    if (T >= NT) return;
    char* dst = lds + buf * BSTRIDE + 16384 + h * (BN * 64) + wave * 1024;
    const char* src = (const char*)B + (col0 + h * (BN / 2)) * rowstride + (long)T * 128;
#pragma unroll
    for (int c = 0; c < BN / 64; ++c) {
      int b = c * 4096 + wave * 1024 + lane * 16;
      int r = b >> 7, cb = b & 127;
      gl_lds16(src + (long)r * rowstride + (cb ^ swz(r)), dst + c * 4096);
    }
  };
  // counted vmcnt: HOPS = ops per (A-half + B-half) stage pair = 2 + BN/64
  auto fence_steady = [&]() {
    if (BN == 192) asm volatile("s_waitcnt vmcnt(5)" ::: "memory");
    else           asm volatile("s_waitcnt vmcnt(4)" ::: "memory");
  };

  // prologue: T0 h0, T0 h1, T1 h0 -> fence completes T0 fully, carry = h0(T1)
  stageA(0, 0, 0); stageB(0, 0, 0);
  stageA(0, 1, 0); stageB(0, 1, 0);
  stageA(1, 0, 1); stageB(1, 0, 1);
  fence_steady();

  for (int g = 0; g < NT; ++g) {
    const int buf = g & 1;
    barrier_np();                          // #1: all waves fenced; buf data ready
    stageA(g + 1, 1, buf ^ 1);             // h1 of next tile -> other buffer
    stageB(g + 1, 1, buf ^ 1);

    bf16x8 a[2][4], b[2][NI];
#pragma unroll
    for (int mi = 0; mi < 4; ++mi) {
      int row = wave_m * 64 + mi * 16 + l16;
      const char* rp = lds + buf * BSTRIDE + row * 128;
      int sw = swz(row);
      a[0][mi] = ds_read128(rp + ((quad * 16) ^ sw));
      a[1][mi] = ds_read128(rp + ((64 + quad * 16) ^ sw));
    }
#pragma unroll
    for (int ni = 0; ni < NI; ++ni) {
      int row = wave_n * (BN / 2) + ni * 16 + l16;
      const char* rp = lds + buf * BSTRIDE + 16384 + row * 128;
      int sw = swz(row);
      b[0][ni] = ds_read128(rp + ((quad * 16) ^ sw));
      b[1][ni] = ds_read128(rp + ((64 + quad * 16) ^ sw));
    }
    WAITL0;                                // my reads done
    barrier_np();                          // #2: everyone's reads done
    stageA(g + 2, 0, buf);                 // overwrite h0 of current buf
    stageB(g + 2, 0, buf);

    __builtin_amdgcn_s_setprio(1);
#pragma unroll
    for (int ks = 0; ks < 2; ++ks)
#pragma unroll
      for (int mi = 0; mi < 4; ++mi)
#pragma unroll
        for (int ni = 0; ni < NI; ++ni)
          acc[mi][ni] = __builtin_amdgcn_mfma_f32_16x16x32_bf16(
              a[ks][mi], b[ks][ni], acc[mi][ni], 0, 0, 0);
    __builtin_amdgcn_s_setprio(0);

    if (g + 2 < NT) fence_steady();
    else            asm volatile("s_waitcnt vmcnt(0)" ::: "memory");
  }

  // epilogue: C write (C/D layout: col=l16, row=quad*4+r per 16x16 frag)
#pragma unroll
  for (int mi = 0; mi < 4; ++mi)
#pragma unroll
    for (int ni = 0; ni < NI; ++ni)
#pragma unroll
      for (int r = 0; r < 4; ++r) {
        long row = row0 + wave_m * 64 + mi * 16 + quad * 4 + r;
        long col = col0 + wave_n * (BN / 2) + ni * 16 + l16;
        float v = acc[mi][ni][r];
        if (CMODE == 1) ((unsigned short*)Cout)[row * N + col] = f2b(v);
        else            ((float*)Cout)[row * N + col] = v;
      }
}

// ------------------------------------------- RoPE + sym int8 quant-dequant + split
// qkv[2048][6144] bf16 -> Qb[32][2048][128], Kb[8][2048][128], Vb[8][2048][128]
__global__ __launch_bounds__(256) void postproc(const unsigned short* __restrict__ qkv,
                                                const int* __restrict__ pos_ids,
                                                unsigned short* __restrict__ Qb,
                                                unsigned short* __restrict__ Kb,
                                                unsigned short* __restrict__ Vb) {
  const int s = blockIdx.x;
  const int lane = threadIdx.x & 63, wave = threadIdx.x >> 6;
  const float pos = (float)pos_ids[s];
  // inv_freq = 10000^(-lane/64) = exp(-lane * ln(10000)/64); pair (d, d+64)
  const float invf = expf(-(float)lane * 0.14391156831212787f);
  const float ang = pos * invf;
  const float ca = cosf(ang), sa = sinf(ang);

  for (int r = wave; r < 48; r += 4) {
    if (r < 32) {                 // Q head r: rope only
      const unsigned short* src = qkv + (long)s * QKV_N + r * HD;
      float x0 = b2f(src[lane]), x1 = b2f(src[lane + 64]);
      unsigned short* dst = Qb + ((long)r * S_LEN + s) * HD;
      dst[lane]      = f2b(x0 * ca - x1 * sa);
      dst[lane + 64] = f2b(x1 * ca + x0 * sa);
    } else if (r < 40) {          // K head r-32: rope then quant-dequant
      int h = r - 32;
      const unsigned short* src = qkv + (long)s * QKV_N + 4096 + h * HD;
      float x0 = b2f(src[lane]), x1 = b2f(src[lane + 64]);
      float y0 = x0 * ca - x1 * sa;
      float y1 = x1 * ca + x0 * sa;
      float m = fmaxf(fabsf(y0), fabsf(y1));
      for (int off = 32; off; off >>= 1) m = fmaxf(m, __shfl_xor(m, off, 64));
      float scale = fmaxf(m / 127.0f, 1e-9f);
      float q0 = fminf(fmaxf(rintf(y0 / scale), -128.f), 127.f);
      float q1 = fminf(fmaxf(rintf(y1 / scale), -128.f), 127.f);
      unsigned short* dst = Kb + ((long)h * S_LEN + s) * HD;
      dst[lane]      = f2b(q0 * scale);
      dst[lane + 64] = f2b(q1 * scale);
    } else {                      // V head r-40: quant-dequant only
      int h = r - 40;
      const unsigned short* src = qkv + (long)s * QKV_N + 5120 + h * HD;
      float x0 = b2f(src[lane]), x1 = b2f(src[lane + 64]);
      float m = fmaxf(fabsf(x0), fabsf(x1));
      for (int off = 32; off; off >>= 1) m = fmaxf(m, __shfl_xor(m, off, 64));
      float scale = fmaxf(m / 127.0f, 1e-9f);
      float q0 = fminf(fmaxf(rintf(x0 / scale), -128.f), 127.f);
      float q1 = fminf(fmaxf(rintf(x1 / scale), -128.f), 127.f);
      unsigned short* dst = Vb + ((long)h * S_LEN + s) * HD;
      dst[lane]      = f2b(q0 * scale);
      dst[lane + 64] = f2b(q1 * scale);
    }
  }
}

// -------------------------------------------------- V transpose: [h][s][d]->[h][d][s]
__global__ __launch_bounds__(256) void transpose_v(const unsigned short* __restrict__ Vb,
                                                   unsigned short* __restrict__ Vtb) {
  __shared__ unsigned short t[64][136];
  const int h = blockIdx.x >> 5, st = blockIdx.x & 31;
  const int tid = threadIdx.x;
  const long vbase = (long)h * S_LEN * HD;
#pragma unroll
  for (int p = 0; p < 8; ++p) {
    int e = p * 1024 + tid * 4;
    int sl = e >> 7, d = e & 127;
    ushort4 v = *(const ushort4*)(Vb + vbase + (long)(st * 64 + sl) * HD + d);
    t[sl][d] = v.x; t[sl][d + 1] = v.y; t[sl][d + 2] = v.z; t[sl][d + 3] = v.w;
  }
  __syncthreads();
  const long tbase = (long)h * HD * S_LEN;
#pragma unroll
  for (int p = 0; p < 8; ++p) {
    int o = p * 1024 + tid * 4;
    int d = o >> 6, sl = o & 63;
    ushort4 v;
    v.x = t[sl][d]; v.y = t[sl + 1][d]; v.z = t[sl + 2][d]; v.w = t[sl + 3][d];
    *(ushort4*)(Vtb + tbase + (long)d * S_LEN + st * 64 + sl) = v;
  }
}

// ------------------------------------------------------------- flash attention
// Block = (head, 128-row q-tile), 4 waves x 32 q-rows. KVBLK=64.
// K tile [64 keys][128 d] and Vt tile [128 d][64 keys] staged in LDS via
// global_load_lds (shared by all waves), double-buffered 2-phase:
//   barrier(drains prev stage) -> issue stage(t+1) -> compute(t).
// XOR swizzle on K/Vt/Ps rows applied on BOTH the pre-swizzled global source
// (linear LDS dest, rule #21) and the ds_read/ds_write side -> conflict-free.
// LDS: K 2x16K + Vt 2x16K + Ps 16K = 80 KB exactly -> 2 blocks/CU.
// Complementary qt pairing: steps/pair = (2qt+2)+(2(15-qt)+2) = 34, balanced.
__global__ __launch_bounds__(256, 2) void attn_kernel(const unsigned short* __restrict__ Qb,
                                                      const unsigned short* __restrict__ Kb,
                                                      const unsigned short* __restrict__ Vtb,
                                                      unsigned short* __restrict__ Ob) {
  __shared__ __align__(16) char lds[81920];
  // layout: K buf0 @0, K buf1 @16384, V buf0 @32768, V buf1 @49152, Ps @65536

  const int bx = blockIdx.x;
  const int p8 = bx & 1;
  const int g = (bx >> 1) & 7;
  const int b8 = bx >> 8;
  const int qt = (p8 ^ b8) ? (15 - g) : g;
  const int h = ((bx >> 4) & 15) + 16 * b8;
  const int hk = h >> 2;                        // GQA: 4 q-heads per kv-head
  const int tid = threadIdx.x;
  const int lane = tid & 63, wave = tid >> 6;
  const int quad = lane >> 4, l16 = lane & 15;

  // Q fragments for this wave's 32 rows (A-operand layout), from global
  bf16x8 qf[2][4];
  {
    const unsigned short* qb =
        Qb + ((long)h * S_LEN + qt * 128 + wave * 32 + l16) * HD + quad * 8;
#pragma unroll
    for (int mi = 0; mi < 2; ++mi)
#pragma unroll
      for (int ks = 0; ks < 4; ++ks)
        qf[mi][ks] = *(const bf16x8*)(qb + mi * 16 * HD + ks * 32);
  }

  f32x4 O[2][8] = {};
  float mrow[2][4], lrow[2][4];
#pragma unroll
  for (int mi = 0; mi < 2; ++mi)
#pragma unroll
    for (int r = 0; r < 4; ++r) { mrow[mi][r] = -1e30f; lrow[mi][r] = 0.f; }

  const char* Kg = (const char*)(Kb + (long)hk * S_LEN * HD);
  const char* Vg = (const char*)(Vtb + (long)hk * HD * S_LEN);
  char* PsB = lds + 65536;
  const float sscale = 0.08838834764831845f;  // 1/sqrt(128)
  const int nsteps = 2 * qt + 2;              // 64-key steps

  // stage one 64-key K tile (16 KB, contiguous rows in global) into buf
  auto stageK = [&](int step, int buf) {
    char* dst = lds + buf * 16384 + wave * 1024;
    const char* src = Kg + (long)step * 16384;
#pragma unroll
    for (int c = 0; c < 4; ++c) {
      int f = c * 4096 + tid * 16;
      int row = f >> 8, wb = f & 255;
      gl_lds16(src + row * 256 + (wb ^ swz(row)), dst + c * 4096);
    }
  };
  // stage one Vt tile [128 d][64 keys] (d-rows strided 4096B in global)
  auto stageV = [&](int step, int buf) {
    char* dst = lds + 32768 + buf * 16384 + wave * 1024;
    const char* src = Vg + (long)step * 128;
#pragma unroll
    for (int c = 0; c < 4; ++c) {
      int f = c * 4096 + tid * 16;
      int d = f >> 7, wb = f & 127;
      gl_lds16(src + (long)d * (S_LEN * 2) + (wb ^ swz(d)), dst + c * 4096);
    }
  };

  stageK(0, 0);
  stageV(0, 0);

  for (int t = 0; t < nsteps; ++t) {
    __syncthreads();   // drains this wave's stage (vmcnt 0) + syncs all waves
    if (t + 1 < nsteps) {
      stageK(t + 1, (t + 1) & 1);
      stageV(t + 1, (t + 1) & 1);
    }
    const char* Ks = lds + (t & 1) * 16384;
    const char* Vs = lds + 32768 + (t & 1) * 16384;

    // ---- S = Q K^T over 64 keys (4 ni of 16)
    f32x4 S[2][4] = {};
    __builtin_amdgcn_s_setprio(1);
#pragma unroll
    for (int ni = 0; ni < 4; ++ni) {
      const int row = ni * 16 + l16;
      const char* kr = Ks + row * 256;
      const int sw = swz(row);
      const int q16 = quad * 16;
      bf16x8 kf0 = *(const bf16x8*)(kr + ((q16 + 0)   ^ sw));
      bf16x8 kf1 = *(const bf16x8*)(kr + ((q16 + 64)  ^ sw));
      bf16x8 kf2 = *(const bf16x8*)(kr + ((q16 + 128) ^ sw));
      bf16x8 kf3 = *(const bf16x8*)(kr + ((q16 + 192) ^ sw));
      S[0][ni] = __builtin_amdgcn_mfma_f32_16x16x32_bf16(qf[0][0], kf0, S[0][ni], 0, 0, 0);
      S[1][ni] = __builtin_amdgcn_mfma_f32_16x16x32_bf16(qf[1][0], kf0, S[1][ni], 0, 0, 0);
      S[0][ni] = __builtin_amdgcn_mfma_f32_16x16x32_bf16(qf[0][1], kf1, S[0][ni], 0, 0, 0);
      S[1][ni] = __builtin_amdgcn_mfma_f32_16x16x32_bf16(qf[1][1], kf1, S[1][ni], 0, 0, 0);
      S[0][ni] = __builtin_amdgcn_mfma_f32_16x16x32_bf16(qf[0][2], kf2, S[0][ni], 0, 0, 0);
      S[1][ni] = __builtin_amdgcn_mfma_f32_16x16x32_bf16(qf[1][2], kf2, S[1][ni], 0, 0, 0);
      S[0][ni] = __builtin_amdgcn_mfma_f32_16x16x32_bf16(qf[0][3], kf3, S[0][ni], 0, 0, 0);
      S[1][ni] = __builtin_amdgcn_mfma_f32_16x16x32_bf16(qf[1][3], kf3, S[1][ni], 0, 0, 0);
    }
    __builtin_amdgcn_s_setprio(0);

    // ---- scale + causal mask + row max
    const bool diag = (t >= 2 * qt);
    const int qrow_base = qt * 128 + wave * 32;
    float rmax[2][4];
#pragma unroll
    for (int mi = 0; mi < 2; ++mi)
#pragma unroll
      for (int r = 0; r < 4; ++r) rmax[mi][r] = -1e30f;
#pragma unroll
    for (int mi = 0; mi < 2; ++mi)
#pragma unroll
      for (int ni = 0; ni < 4; ++ni) {
        int col = t * 64 + ni * 16 + l16;
#pragma unroll
        for (int r = 0; r < 4; ++r) {
          int row = qrow_base + mi * 16 + quad * 4 + r;
          float v = S[mi][ni][r] * sscale;
          if (diag && col > row) v = -1e9f;
          S[mi][ni][r] = v;
          rmax[mi][r] = fmaxf(rmax[mi][r], v);
        }
      }
    float alpha[2][4], rsum[2][4];
#pragma unroll
    for (int mi = 0; mi < 2; ++mi)
#pragma unroll
      for (int r = 0; r < 4; ++r) {
        float v = rmax[mi][r];
        v = fmaxf(v, __shfl_xor(v, 1, 64));
        v = fmaxf(v, __shfl_xor(v, 2, 64));
        v = fmaxf(v, __shfl_xor(v, 4, 64));
        v = fmaxf(v, __shfl_xor(v, 8, 64));
        float mnew = fmaxf(mrow[mi][r], v);
        alpha[mi][r] = __expf(mrow[mi][r] - mnew);
        mrow[mi][r] = mnew;
        rsum[mi][r] = 0.f;
      }

    // ---- P = exp(S - m) -> wave-local swizzled LDS rows, accumulate sums
#pragma unroll
    for (int mi = 0; mi < 2; ++mi)
#pragma unroll
      for (int ni = 0; ni < 4; ++ni)
#pragma unroll
        for (int r = 0; r < 4; ++r) {
          float p = __expf(S[mi][ni][r] - mrow[mi][r]);
          rsum[mi][r] += p;
          int prow = wave * 32 + mi * 16 + quad * 4 + r;
          int pcol2 = (ni * 16 + l16) * 2;
          *(unsigned short*)(PsB + prow * 128 + (pcol2 ^ swz(prow))) = f2b(p);
        }
#pragma unroll
    for (int mi = 0; mi < 2; ++mi)
#pragma unroll
      for (int r = 0; r < 4; ++r) {
        float v = rsum[mi][r];
        v += __shfl_xor(v, 1, 64);
        v += __shfl_xor(v, 2, 64);
        v += __shfl_xor(v, 4, 64);
        v += __shfl_xor(v, 8, 64);
        lrow[mi][r] = lrow[mi][r] * alpha[mi][r] + v;
      }
#pragma unroll
    for (int mi = 0; mi < 2; ++mi)
#pragma unroll
      for (int ni = 0; ni < 8; ++ni)
#pragma unroll
        for (int r = 0; r < 4; ++r) O[mi][ni][r] *= alpha[mi][r];

    // ---- O += P V : P A-frags from wave-local LDS, Vt B-frags from LDS tile
    bf16x8 pf[2][2];
#pragma unroll
    for (int mi = 0; mi < 2; ++mi)
#pragma unroll
      for (int ks2 = 0; ks2 < 2; ++ks2) {
        int prow = wave * 32 + mi * 16 + l16;
        pf[mi][ks2] = *(const bf16x8*)(PsB + prow * 128 +
                                       ((ks2 * 64 + quad * 16) ^ swz(prow)));
      }
    __builtin_amdgcn_s_setprio(1);
#pragma unroll
    for (int ni = 0; ni < 8; ++ni) {
      const int row = ni * 16 + l16;
      const char* vr = Vs + row * 128;
      const int sw = swz(row);
      const int q16 = quad * 16;
      bf16x8 vf0 = *(const bf16x8*)(vr + ((q16 + 0)  ^ sw));
      bf16x8 vf1 = *(const bf16x8*)(vr + ((q16 + 64) ^ sw));
      O[0][ni] = __builtin_amdgcn_mfma_f32_16x16x32_bf16(pf[0][0], vf0, O[0][ni], 0, 0, 0);
      O[1][ni] = __builtin_amdgcn_mfma_f32_16x16x32_bf16(pf[1][0], vf0, O[1][ni], 0, 0, 0);
      O[0][ni] = __builtin_amdgcn_mfma_f32_16x16x32_bf16(pf[0][1], vf1, O[0][ni], 0, 0, 0);
      O[1][ni] = __builtin_amdgcn_mfma_f32_16x16x32_bf16(pf[1][1], vf1, O[1][ni], 0, 0, 0);
    }
    __builtin_amdgcn_s_setprio(0);
  }

  // normalize + store bf16 at [s][h*128+d]
#pragma unroll
  for (int mi = 0; mi < 2; ++mi)
#pragma unroll
    for (int r = 0; r < 4; ++r) {
      float inv = 1.0f / lrow[mi][r];
      long srow = qt * 128 + wave * 32 + mi * 16 + quad * 4 + r;
#pragma unroll
      for (int ni = 0; ni < 8; ++ni) {
        long col = (long)h * HD + ni * 16 + l16;
        Ob[srow * (long)HID + col] = f2b(O[mi][ni][r] * inv);
      }
    }
}

// ---------------------------------------------------------------------------
extern "C" void kernel_launch(void* const* d_in, const int* in_sizes, int n_in,
                              void* d_out, int out_size, void* d_ws, size_t ws_size,
                              hipStream_t stream) {
  const float* hidden = (const float*)d_in[0];
  const float* wq = (const float*)d_in[1];
  const float* wk = (const float*)d_in[2];
  const float* wv = (const float*)d_in[3];
  const float* wo = (const float*)d_in[4];
  const int* pos = (const int*)d_in[5];
  float* out = (float*)d_out;

  // workspace layout (bytes); total 138,412,032. Overlays: Qb=hid_b (hid dead
  // after GEMM1), attn_b=qkv_b (qkv dead after postproc).
  char* ws = (char*)d_ws;
  unsigned short* wqkv_b = (unsigned short*)(ws);               // 50,331,648
  unsigned short* wo_b   = (unsigned short*)(ws + 50331648);    // 33,554,432
  unsigned short* hid_b  = (unsigned short*)(ws + 83886080);    // 16,777,216
  unsigned short* qkv_b  = (unsigned short*)(ws + 100663296);   // 25,165,824
  unsigned short* Kb     = (unsigned short*)(ws + 125829120);   //  4,194,304
  unsigned short* Vb     = (unsigned short*)(ws + 130023424);   //  4,194,304
  unsigned short* Vtb    = (unsigned short*)(ws + 134217728);   //  4,194,304
  unsigned short* Qb     = hid_b;
  unsigned short* attn_b = qkv_b;

  cast_kernel<<<8388608 / 1024, 256, 0, stream>>>(hidden, hid_b, 8388608 / 4);
  cast_kernel<<<16777216 / 1024, 256, 0, stream>>>(wq, wqkv_b, 16777216 / 4);
  cast_kernel<<<4194304 / 1024, 256, 0, stream>>>(wk, wqkv_b + 16777216, 4194304 / 4);
  cast_kernel<<<4194304 / 1024, 256, 0, stream>>>(wv, wqkv_b + 20971520, 4194304 / 4);
  cast_kernel<<<16777216 / 1024, 256, 0, stream>>>(wo, wo_b, 16777216 / 4);

  // QKV: 128x192 tiles -> grid 32x16 = 512 blocks = 2/CU, 100% fill
  gemm_bt<192, 1><<<dim3(QKV_N / 192, S_LEN / 128), 256, 0, stream>>>(
      hid_b, wqkv_b, (void*)qkv_b, S_LEN, QKV_N, HID);

  postproc<<<S_LEN, 256, 0, stream>>>(qkv_b, pos, Qb, Kb, Vb);
  transpose_v<<<NKV * 32, 256, 0, stream>>>(Vb, Vtb);
  attn_kernel<<<NH * 16, 256, 0, stream>>>(Qb, Kb, Vtb, attn_b);

  // out-proj: 128x128 tiles -> grid 32x16 = 512 blocks = 2/CU, 100% fill
  gemm_bt<128, 0><<<dim3(HID / 128, S_LEN / 128), 256, 0, stream>>>(
      attn_b, wo_b, (void*)out, S_LEN, HID, HID);
}